// Round 14
// baseline (2897.071 us; speedup 1.0000x reference)
//
#include <hip/hip_runtime.h>
#include <cstddef>
#include <cstdint>

typedef __attribute__((ext_vector_type(8))) _Float16 half8;
typedef __attribute__((ext_vector_type(4))) _Float16 half4;
typedef __attribute__((ext_vector_type(4))) float f32x4;

static __device__ __forceinline__ unsigned packhl(float v) {
  _Float16 h = (_Float16)v;
  _Float16 l = (_Float16)((v - (float)h) * 2048.0f);
  return (unsigned)__builtin_bit_cast(unsigned short, h) |
         ((unsigned)__builtin_bit_cast(unsigned short, l) << 16);
}

// ---------------------------------------------------------------------------
// VQ-VAE forward. MFMA f16 2-term-split tap-GEMM for conv2/conv3/convT1/convT2.
// R14: convT2 staged via global_load_lds from split h/l planes (convT1 now
// writes d1 in the same 32c8x66x66 bordered layout h2 uses — borders zeroed
// once per chunk serve both). convT LDS k8-stride padded 72->74 (bank stagger).
// Math order identical R5-R13 (bit-identical outputs).
// ---------------------------------------------------------------------------

// Pre-split conv weights: W[Cout][CIN][4][4] -> [tap][cb][k8][cout][8] f16 h/l
template<int CIN>
__global__ __launch_bounds__(256) void wsplit_k(
    const float* __restrict__ W, _Float16* __restrict__ Wh,
    _Float16* __restrict__ Wl, int Cout) {
  constexpr int NCB = CIN / 32;
  int idx = blockIdx.x * 256 + threadIdx.x;
  if (idx >= Cout * CIN) return;
  int ci = idx % CIN, co = idx / CIN;
  int cb = ci >> 5, k8 = (ci >> 3) & 3, j = ci & 7;
  const float* wp = W + (size_t)idx * 16;
#pragma unroll
  for (int tap = 0; tap < 16; ++tap) {
    float w = wp[tap];
    _Float16 wh = (_Float16)w;
    _Float16 wl = (_Float16)((w - (float)wh) * 2048.0f);
    size_t o = (((size_t)(tap * NCB + cb) * 4 + k8) * Cout + co) * 8 + j;
    Wh[o] = wh; Wl[o] = wl;
  }
}

// Pre-split convT weights: W[CIN][Cout][4][4] -> [t][cb][k8][cout][8] f16 h/l
template<int CIN>
__global__ __launch_bounds__(256) void wsplitT_k(
    const float* __restrict__ W, _Float16* __restrict__ Wh,
    _Float16* __restrict__ Wl, int Cout) {
  constexpr int NCB = CIN / 32;
  int idx = blockIdx.x * 256 + threadIdx.x;
  if (idx >= CIN * Cout) return;
  int co = idx % Cout, ci = idx / Cout;
  int cb = ci >> 5, k8 = (ci >> 3) & 3, j = ci & 7;
  const float* wp = W + (size_t)idx * 16;
#pragma unroll
  for (int t = 0; t < 16; ++t) {
    int py = (t >> 3) & 1, px = (t >> 2) & 1, i0 = (t >> 1) & 1, i1 = t & 1;
    int kh = py ? (i0 ? 2 : 0) : (i0 ? 3 : 1);
    int kw = px ? (i1 ? 2 : 0) : (i1 ? 3 : 1);
    float w = wp[kh * 4 + kw];
    _Float16 wh = (_Float16)w;
    _Float16 wl = (_Float16)((w - (float)wh) * 2048.0f);
    size_t o = (((size_t)(t * NCB + cb) * 4 + k8) * Cout + co) * 8 + j;
    Wh[o] = wh; Wl[o] = wl;
  }
}

// Zero the 1-px border of split h/l planes. H2/W2 = padded dims.
__global__ __launch_bounds__(256) void border_k(
    char* base, int c8n, int H2, int W2, size_t SAI, size_t LOFF, int nimg) {
  int nb = 2 * W2 + 2 * (H2 - 2);
  int tot = nimg * c8n * 2 * nb;
  int idx = blockIdx.x * 256 + threadIdx.x;
  if (idx >= tot) return;
  int s = idx % nb; int r = idx / nb;
  int pl = r & 1; r >>= 1;
  int c8 = r % c8n; int b = r / c8n;
  int y, x;
  if (s < W2)            { y = 0;       x = s; }
  else if (s < 2 * W2)   { y = H2 - 1;  x = s - W2; }
  else { int t = s - 2 * W2; y = 1 + (t >> 1); x = (t & 1) ? W2 - 1 : 0; }
  size_t PLANE = (size_t)H2 * W2 * 16;
  char* p = base + (size_t)b * SAI + (size_t)pl * LOFF + (size_t)c8 * PLANE
            + ((size_t)y * W2 + x) * 16;
  *(uint4*)p = make_uint4(0, 0, 0, 0);
}

// MFMA conv k4 s2 p1 (+ReLU). R13-verified.
// SPLITIN=1: split h/l planes (+border) staged via global_load_lds.
// PACKOUT: 0 = f32 NCHW, 2 = split h/l planes.
template<int CIN, int COUT, int CGRP, int NF, int RELU, int PACKOUT, int SPLITIN>
__global__ __launch_bounds__(256) void conv_mfma2(
    const void* __restrict__ inP, const _Float16* __restrict__ Whg,
    const _Float16* __restrict__ Wlg, const float* __restrict__ bias,
    float* __restrict__ out, int Hin, int Win,
    size_t inSAI, size_t inLOFF, size_t outSAI, size_t outLOFF) {
  constexpr int NCB  = CIN / 32;
  constexpr int MT   = COUT / CGRP;
  constexpr int MF   = MT / 64;
  constexpr int ROWS = 2 * NF + 2;
  constexpr int NPOS = ROWS * 34;
  constexpr int K8S  = NPOS + 6;
  const int Hout = Hin >> 1, Wout = Win >> 1;
  const int TW = Wout >> 4;
  __shared__ half8 Bh[4 * K8S], Bl[4 * K8S];
  const int tid = threadIdx.x;
  const int lane = tid & 63, w = tid >> 6;
  const int l15 = lane & 15, k8 = lane >> 4;
  int tx, ty, cg, b;
  {
    unsigned nwg = gridDim.x * gridDim.y;
    unsigned id  = blockIdx.y * gridDim.x + blockIdx.x;
    unsigned sw  = (id & 7) * (nwg >> 3) + (id >> 3);
    const int bx = sw % gridDim.x, by = sw / gridDim.x;
    tx = bx % TW; ty = bx / TW;
    cg = by % CGRP;
    b  = by / CGRP;
  }
  const int oy0 = ty * NF, ox0 = tx << 4;
  const int iy_org = 2 * oy0 - 1, ix_org = 2 * ox0 - 1;
  const int cbase = cg * MT + w * (MT / 4);
  const size_t tapStride = (size_t)NCB * 4 * COUT * 8;

  unsigned goff[4];
  const char* baseh = nullptr;
  size_t PLANE = 0;
  {
    const int W2 = Win + 2;
    PLANE = (size_t)(Hin + 2) * W2 * 16;
    constexpr int S0[4] = {0, 64, 128, NPOS - 64};
#pragma unroll
    for (int t = 0; t < 4; ++t) {
      int s = S0[t] + lane;
      int r = s / 17, c = s - r * 17;
      int hy = r >> 1, p = r & 1;
      int hx = (c << 1) | p;
      int iy = iy_org + hy + 1, ix = ix_org + hx + 1;
      goff[t] = (unsigned)(((size_t)iy * W2 + ix) * 16);
    }
    baseh = (const char*)inP + ((size_t)b * inSAI) + (size_t)w * PLANE;
  }

  f32x4 accM[MF][NF], accX[MF][NF];
#pragma unroll
  for (int m = 0; m < MF; ++m)
#pragma unroll
    for (int nf = 0; nf < NF; ++nf) {
      accM[m][nf] = f32x4{0,0,0,0};
      accX[m][nf] = f32x4{0,0,0,0};
    }

  for (int cb = 0; cb < NCB; ++cb) {
    __syncthreads();
    {
      const char* pc = baseh + (size_t)cb * 4 * PLANE;
      char* lh = (char*)&Bh[w * K8S];
      char* ll = (char*)&Bl[w * K8S];
      constexpr int S0[4] = {0, 64, 128, NPOS - 64};
#pragma unroll
      for (int t = 0; t < 4; ++t) {
        __builtin_amdgcn_global_load_lds(
            (const __attribute__((address_space(1))) void*)(pc + goff[t]),
            (__attribute__((address_space(3))) void*)(lh + S0[t] * 16), 16, 0, 0);
        __builtin_amdgcn_global_load_lds(
            (const __attribute__((address_space(1))) void*)(pc + inLOFF + goff[t]),
            (__attribute__((address_space(3))) void*)(ll + S0[t] * 16), 16, 0, 0);
      }
    }
    __syncthreads();
    const _Float16* aph = Whg + (((size_t)cb * 4 + k8) * COUT + cbase + l15) * 8;
    const _Float16* apl = Wlg + (((size_t)cb * 4 + k8) * COUT + cbase + l15) * 8;
    half8 ah[2][MF], al[2][MF];
#pragma unroll
    for (int m = 0; m < MF; ++m) {
      ah[0][m] = *(const half8*)(aph + m * 128);
      al[0][m] = *(const half8*)(apl + m * 128);
    }
#pragma unroll
    for (int tp = 0; tp < 16; ++tp) {
      const int cur = tp & 1, nxt = cur ^ 1;
      if (tp < 15) {
#pragma unroll
        for (int m = 0; m < MF; ++m) {
          ah[nxt][m] = *(const half8*)(aph + (size_t)(tp + 1) * tapStride + m * 128);
          al[nxt][m] = *(const half8*)(apl + (size_t)(tp + 1) * tapStride + m * 128);
        }
      }
      const int kh = tp >> 2, kw = tp & 3;
      const int p = kw & 1, cidx = kw >> 1;
#pragma unroll
      for (int nf = 0; nf < NF; ++nf) {
        const int slot = k8 * K8S + ((2 * nf + kh) * 2 + p) * 17 + l15 + cidx;
        const half8 bh = Bh[slot], bl = Bl[slot];
#pragma unroll
        for (int m = 0; m < MF; ++m) {
          accM[m][nf] = __builtin_amdgcn_mfma_f32_16x16x32_f16(ah[cur][m], bh, accM[m][nf], 0, 0, 0);
          accX[m][nf] = __builtin_amdgcn_mfma_f32_16x16x32_f16(ah[cur][m], bl, accX[m][nf], 0, 0, 0);
          accX[m][nf] = __builtin_amdgcn_mfma_f32_16x16x32_f16(al[cur][m], bh, accX[m][nf], 0, 0, 0);
        }
      }
    }
  }
  // ---- epilogue ----
#pragma unroll
  for (int m = 0; m < MF; ++m)
#pragma unroll
    for (int nf = 0; nf < NF; ++nf) {
      int oy = oy0 + nf, ox = ox0 + l15;
      if (PACKOUT == 2) {
        const int W2o = Wout + 2;
        const size_t PLANEo = (size_t)(Hout + 2) * W2o * 16;
        half4 hv, lv;
#pragma unroll
        for (int i = 0; i < 4; ++i) {
          int co = cbase + m * 16 + k8 * 4 + i;
          float v = accM[m][nf][i] + accX[m][nf][i] * (1.0f / 2048.0f) + bias[co];
          if (RELU) v = fmaxf(v, 0.0f);
          _Float16 h = (_Float16)v;
          hv[i] = h; lv[i] = (_Float16)((v - (float)h) * 2048.0f);
        }
        int c8 = (cbase + m * 16 + k8 * 4) >> 3;
        int j0 = (k8 & 1) * 4;
        char* ob = (char*)out + (size_t)b * outSAI + (size_t)c8 * PLANEo
                   + (((size_t)(oy + 1) * W2o) + ox + 1) * 16 + j0 * 2;
        *(half4*)ob = hv;
        *(half4*)(ob + outLOFF) = lv;
      } else {
#pragma unroll
        for (int i = 0; i < 4; ++i) {
          int co = cbase + m * 16 + k8 * 4 + i;
          float v = accM[m][nf][i] + accX[m][nf][i] * (1.0f / 2048.0f) + bias[co];
          if (RELU) v = fmaxf(v, 0.0f);
          out[(((size_t)b * COUT + co) * Hout + oy) * Wout + ox] = v;
        }
      }
    }
}

// MFMA convT k4 s2 p1 (+ReLU). Parity decomposition (R8 shape).
// PACKIN: 0 = f32 NCHW (reg-staged), 2 = split h/l planes via global_load_lds.
// PACKOUT: 0 = f32 NCHW, 2 = split h/l planes (+border).
template<int CIN, int COUT, int CGRP, int RELU, int PACKIN, int PACKOUT, int SWZ>
__global__ __launch_bounds__(256) void convT_mfma(
    const void* __restrict__ inP, const _Float16* __restrict__ Whg,
    const _Float16* __restrict__ Wlg, const float* __restrict__ bias,
    float* __restrict__ out, int Hin, int Win,
    size_t inSAI, size_t inLOFF, size_t outSAI, size_t outLOFF) {
  constexpr int NCB  = CIN / 32;
  constexpr int MT   = COUT / CGRP;
  constexpr int MF   = MT / 64;
  constexpr int K8ST = 74;          // 72 slots + 2 pad (8-bank k8 stagger)
  const int Hout = Hin * 2, Wout = Win * 2;
  const int TW = Win >> 4;
  __shared__ half8 Bh[4 * K8ST], Bl[4 * K8ST];
  const int tid = threadIdx.x;
  const int lane = tid & 63, w = tid >> 6;
  const int l15 = lane & 15, k8 = lane >> 4;
  int bx = blockIdx.x, by = blockIdx.y;
  if (SWZ) {
    unsigned nwg = gridDim.x * gridDim.y;
    unsigned id  = (unsigned)by * gridDim.x + bx;
    unsigned sw  = (id & 7) * (nwg >> 3) + (id >> 3);
    bx = (int)(sw % gridDim.x); by = (int)(sw / gridDim.x);
  }
  const int tx = bx % TW, ty = bx / TW;
  const int cg = by % CGRP;
  const int b  = by / CGRP;
  const int ty0 = ty << 1, tx0 = tx << 4;
  const int cbase = cg * MT + w * (MT / 4);
  const size_t HW = (size_t)Hin * Win;
  const size_t tapStride = (size_t)NCB * 4 * COUT * 8;

  // PACKIN==2: per-lane DMA source offsets (spans {0,8} of 72 slots)
  unsigned goffT[2];
  const char* basehT = nullptr;
  size_t PLANET = 0;
  if (PACKIN == 2) {
    const int W2 = Win + 2;
    PLANET = (size_t)(Hin + 2) * W2 * 16;
    constexpr int S0T[2] = {0, 8};
#pragma unroll
    for (int t = 0; t < 2; ++t) {
      int s = S0T[t] + lane;
      int r = s / 18, c = s - r * 18;
      goffT[t] = (unsigned)(((size_t)(ty0 + r) * W2 + (tx0 + c)) * 16);
    }
    basehT = (const char*)inP + ((size_t)b * inSAI) + (size_t)w * PLANET;
  }

  f32x4 accM[MF][4][2], accX[MF][4][2];
#pragma unroll
  for (int m = 0; m < MF; ++m)
#pragma unroll
    for (int p = 0; p < 4; ++p)
#pragma unroll
      for (int nf = 0; nf < 2; ++nf) {
        accM[m][p][nf] = f32x4{0,0,0,0};
        accX[m][p][nf] = f32x4{0,0,0,0};
      }

  for (int cb = 0; cb < NCB; ++cb) {
    __syncthreads();
    if (PACKIN == 2) {
      const char* pc = basehT + (size_t)cb * 4 * PLANET;
      char* lh = (char*)&Bh[w * K8ST];
      char* ll = (char*)&Bl[w * K8ST];
      constexpr int S0T[2] = {0, 8};
#pragma unroll
      for (int t = 0; t < 2; ++t) {
        __builtin_amdgcn_global_load_lds(
            (const __attribute__((address_space(1))) void*)(pc + goffT[t]),
            (__attribute__((address_space(3))) void*)(lh + S0T[t] * 16), 16, 0, 0);
        __builtin_amdgcn_global_load_lds(
            (const __attribute__((address_space(1))) void*)(pc + inLOFF + goffT[t]),
            (__attribute__((address_space(3))) void*)(ll + S0T[t] * 16), 16, 0, 0);
      }
    } else {
      const float* inF = (const float*)inP;
      for (int u = tid; u < 288; u += 256) {
        int pos = u % 72, kk = u / 72;
        int r = pos / 18, c = pos - r * 18;
        int iy = ty0 - 1 + r, ix = tx0 - 1 + c;
        bool ok = (unsigned)iy < (unsigned)Hin && (unsigned)ix < (unsigned)Win;
        const float* gp = inF + ((size_t)b * CIN + cb * 32 + kk * 8) * HW
                          + (ptrdiff_t)iy * Win + ix;
        half8 vh, vl;
#pragma unroll
        for (int j = 0; j < 8; ++j) {
          float x = ok ? gp[(size_t)j * HW] : 0.0f;
          _Float16 xh = (_Float16)x;
          vh[j] = xh; vl[j] = (_Float16)((x - (float)xh) * 2048.0f);
        }
        Bh[kk * K8ST + pos] = vh;
        Bl[kk * K8ST + pos] = vl;
      }
    }
    __syncthreads();
    const _Float16* aph = Whg + (((size_t)cb * 4 + k8) * COUT + cbase + l15) * 8;
    const _Float16* apl = Wlg + (((size_t)cb * 4 + k8) * COUT + cbase + l15) * 8;
    half8 ah[2][MF], al[2][MF];
#pragma unroll
    for (int m = 0; m < MF; ++m) {
      ah[0][m] = *(const half8*)(aph + m * 128);
      al[0][m] = *(const half8*)(apl + m * 128);
    }
#pragma unroll
    for (int t = 0; t < 16; ++t) {
      const int cur = t & 1, nxt = cur ^ 1;
      if (t < 15) {
#pragma unroll
        for (int m = 0; m < MF; ++m) {
          ah[nxt][m] = *(const half8*)(aph + (size_t)(t + 1) * tapStride + m * 128);
          al[nxt][m] = *(const half8*)(apl + (size_t)(t + 1) * tapStride + m * 128);
        }
      }
      const int py = (t >> 3) & 1, px = (t >> 2) & 1;
      const int i0 = (t >> 1) & 1, i1 = t & 1;
      const int dy = py ? (i0 ? 0 : 1) : (i0 ? -1 : 0);
      const int dx = px ? (i1 ? 0 : 1) : (i1 ? -1 : 0);
      const int p = py * 2 + px;
#pragma unroll
      for (int nf = 0; nf < 2; ++nf) {
        int slot = k8 * K8ST + (nf + 1 + dy) * 18 + (l15 + 1 + dx);
        half8 bh = Bh[slot], bl = Bl[slot];
#pragma unroll
        for (int m = 0; m < MF; ++m) {
          accM[m][p][nf] = __builtin_amdgcn_mfma_f32_16x16x32_f16(ah[cur][m], bh, accM[m][p][nf], 0, 0, 0);
          accX[m][p][nf] = __builtin_amdgcn_mfma_f32_16x16x32_f16(ah[cur][m], bl, accX[m][p][nf], 0, 0, 0);
          accX[m][p][nf] = __builtin_amdgcn_mfma_f32_16x16x32_f16(al[cur][m], bh, accX[m][p][nf], 0, 0, 0);
        }
      }
    }
  }
#pragma unroll
  for (int m = 0; m < MF; ++m) {
    const int co0m = cbase + m * 16;
#pragma unroll
    for (int nf = 0; nf < 2; ++nf) {
#pragma unroll
      for (int py = 0; py < 2; ++py) {
        int oy = 2 * (ty0 + nf) + py, ox = 2 * (tx0 + l15);
        if (PACKOUT == 2) {
          const int W2o = Wout + 2;
          const size_t PLANEo = (size_t)(Hout + 2) * W2o * 16;
          half4 hv0, lv0, hv1, lv1;
#pragma unroll
          for (int i = 0; i < 4; ++i) {
            int co = co0m + k8 * 4 + i;
            float bb = bias[co];
            float v0 = accM[m][py * 2 + 0][nf][i] + accX[m][py * 2 + 0][nf][i] * (1.0f / 2048.0f) + bb;
            float v1 = accM[m][py * 2 + 1][nf][i] + accX[m][py * 2 + 1][nf][i] * (1.0f / 2048.0f) + bb;
            if (RELU) { v0 = fmaxf(v0, 0.0f); v1 = fmaxf(v1, 0.0f); }
            _Float16 h0 = (_Float16)v0, h1 = (_Float16)v1;
            hv0[i] = h0; lv0[i] = (_Float16)((v0 - (float)h0) * 2048.0f);
            hv1[i] = h1; lv1[i] = (_Float16)((v1 - (float)h1) * 2048.0f);
          }
          int c8 = (co0m + k8 * 4) >> 3;
          int j0 = (k8 & 1) * 4;
          char* ob = (char*)out + (size_t)b * outSAI + (size_t)c8 * PLANEo
                     + (((size_t)(oy + 1) * W2o) + ox + 1) * 16 + j0 * 2;
          *(half4*)ob = hv0;
          *(half4*)(ob + 16) = hv1;
          *(half4*)(ob + outLOFF) = lv0;
          *(half4*)(ob + outLOFF + 16) = lv1;
        } else {
#pragma unroll
          for (int i = 0; i < 4; ++i) {
            int co = co0m + k8 * 4 + i;
            float bb = bias[co];
            float v0 = accM[m][py * 2 + 0][nf][i] + accX[m][py * 2 + 0][nf][i] * (1.0f / 2048.0f) + bb;
            float v1 = accM[m][py * 2 + 1][nf][i] + accX[m][py * 2 + 1][nf][i] * (1.0f / 2048.0f) + bb;
            if (RELU) { v0 = fmaxf(v0, 0.0f); v1 = fmaxf(v1, 0.0f); }
            *(float2*)((float*)out + (((size_t)b * COUT + co) * Hout + oy) * Wout + ox) =
                make_float2(v0, v1);
          }
        }
      }
    }
  }
}

// ---------------- f32 kernels ----------------------------------------------

template<int CIN, int G, int RELU, int PACKOUT>
__global__ __launch_bounds__(256) void conv_t(
    const float* __restrict__ in, const float* __restrict__ wt,
    const float* __restrict__ bias, float* __restrict__ out,
    int Cout, int Hin, int Win, size_t oSAI, size_t oLOFF) {
  const int Hout = Hin >> 1, Wout = Win >> 1;
  const int TW = Wout >> 4;
  __shared__ float tile[34 * 35];
  int tid = threadIdx.x;
  int oxl = tid & 15, oyl = tid >> 4;
  int tyt = blockIdx.x / TW, txt = blockIdx.x - tyt * TW;
  int oy0 = tyt << 4, ox0 = txt << 4;
  int cg = blockIdx.y % (Cout / G);
  int b  = blockIdx.y / (Cout / G);
  int co0 = cg * G;
  const int iy_org = 2 * oy0 - 1, ix_org = 2 * ox0 - 1;
  const float* ip = in + (size_t)b * CIN * Hin * Win;
  float acc[G];
#pragma unroll
  for (int j = 0; j < G; ++j) acc[j] = bias[co0 + j];
  const int lbase = (2 * oyl) * 35 + 2 * oxl;
  for (int ci = 0; ci < CIN; ++ci) {
    const float* ic = ip + (size_t)ci * Hin * Win;
    __syncthreads();
#pragma unroll
    for (int k = 0; k < 5; ++k) {
      int idx = tid + k * 256;
      if (idx < 34 * 34) {
        int r = idx / 34, c = idx - r * 34;
        int iy = iy_org + r, ix = ix_org + c;
        float v = ((unsigned)iy < (unsigned)Hin && (unsigned)ix < (unsigned)Win)
                      ? ic[(size_t)iy * Win + ix] : 0.0f;
        tile[r * 35 + c] = v;
      }
    }
    __syncthreads();
    float xv[16];
#pragma unroll
    for (int kh = 0; kh < 4; ++kh)
#pragma unroll
      for (int kw = 0; kw < 4; ++kw)
        xv[kh * 4 + kw] = tile[lbase + kh * 35 + kw];
    const float* wc = wt + ((size_t)co0 * CIN + ci) * 16;
#pragma unroll
    for (int j = 0; j < G; ++j) {
      const float* wj = wc + (size_t)j * CIN * 16;
#pragma unroll
      for (int t2 = 0; t2 < 16; ++t2) acc[j] = fmaf(xv[t2], wj[t2], acc[j]);
    }
  }
  int oy = oy0 + oyl, ox = ox0 + oxl;
  if (RELU) {
#pragma unroll
    for (int j = 0; j < G; ++j) acc[j] = fmaxf(acc[j], 0.0f);
  }
  if (PACKOUT == 2) {
    const int W2 = Wout + 2;
    const size_t PLANE = (size_t)(Hout + 2) * W2 * 16;
    char* ob0 = (char*)out + (size_t)b * oSAI
                + ((size_t)(oy + 1) * W2 + ox + 1) * 16;
#pragma unroll
    for (int mb = 0; mb < G / 8; ++mb) {
      half8 hv, lv;
#pragma unroll
      for (int j = 0; j < 8; ++j) {
        float v = acc[mb * 8 + j];
        _Float16 h = (_Float16)v;
        hv[j] = h; lv[j] = (_Float16)((v - (float)h) * 2048.0f);
      }
      char* ob = ob0 + (size_t)((co0 >> 3) + mb) * PLANE;
      *(half8*)ob = hv;
      *(half8*)(ob + oLOFF) = lv;
    }
  } else {
    size_t cs = (size_t)Hout * Wout;
    float* op = out + ((size_t)(b * Cout + co0) * Hout + oy) * Wout + ox;
#pragma unroll
    for (int j = 0; j < G; ++j) op[(size_t)j * cs] = acc[j];
  }
}

template<int CIN, int G>
__global__ __launch_bounds__(256) void conv1x1_k(
    const float* __restrict__ in, const float* __restrict__ wt,
    const float* __restrict__ bias, float* __restrict__ out,
    int Cout, int HW) {
  int hw = blockIdx.x * 256 + threadIdx.x;
  int cg = blockIdx.y % (Cout / G);
  int b  = blockIdx.y / (Cout / G);
  int co0 = cg * G;
  const float* ip = in + (size_t)b * CIN * HW + hw;
  float acc[G];
#pragma unroll
  for (int j = 0; j < G; ++j) acc[j] = bias[co0 + j];
#pragma unroll 4
  for (int ci = 0; ci < CIN; ++ci) {
    float xv = ip[(size_t)ci * HW];
#pragma unroll
    for (int j = 0; j < G; ++j)
      acc[j] = fmaf(xv, wt[(size_t)(co0 + j) * CIN + ci], acc[j]);
  }
  float* op = out + ((size_t)(b * Cout + co0)) * HW + hw;
#pragma unroll
  for (int j = 0; j < G; ++j) op[(size_t)j * HW] = acc[j];
}

__global__ __launch_bounds__(128) void vq_k(
    const float* __restrict__ ze, const float* __restrict__ emb,
    float* __restrict__ zq, float* __restrict__ partial) {
  __shared__ float4 se4[128 * 16];
  __shared__ float red[128];
  int tid = threadIdx.x;
  int gid = blockIdx.x * 128 + tid;
  int b = gid >> 10, n = gid & 1023;
  const float* zp = ze + ((size_t)b << 16) + n;
  float4 v4[16];
#pragma unroll
  for (int d = 0; d < 16; ++d) {
    v4[d].x = zp[(size_t)(4 * d + 0) << 10];
    v4[d].y = zp[(size_t)(4 * d + 1) << 10];
    v4[d].z = zp[(size_t)(4 * d + 2) << 10];
    v4[d].w = zp[(size_t)(4 * d + 3) << 10];
  }
  float best = 1e30f; int bi = 0;
  for (int c = 0; c < 4; ++c) {
    __syncthreads();
    for (int i = tid; i < 2048; i += 128)
      se4[i] = ((const float4*)emb)[(c << 11) + i];
    __syncthreads();
    for (int k = 0; k < 128; ++k) {
      const float4* e = se4 + (k << 4);
      float s = 0.0f;
#pragma unroll
      for (int d = 0; d < 16; ++d) {
        float4 ev = e[d];
        float t0 = v4[d].x - ev.x; s = fmaf(t0, t0, s);
        float t1 = v4[d].y - ev.y; s = fmaf(t1, t1, s);
        float t2 = v4[d].z - ev.z; s = fmaf(t2, t2, s);
        float t3 = v4[d].w - ev.w; s = fmaf(t3, t3, s);
      }
      if (s < best) { best = s; bi = (c << 7) + k; }
    }
  }
  const float4* eb4 = (const float4*)emb + ((size_t)bi << 4);
  float* qp = zq + ((size_t)b << 16) + n;
  float ls = 0.0f;
#pragma unroll
  for (int d = 0; d < 16; ++d) {
    float4 q = eb4[d];
    qp[(size_t)(4 * d + 0) << 10] = q.x;
    qp[(size_t)(4 * d + 1) << 10] = q.y;
    qp[(size_t)(4 * d + 2) << 10] = q.z;
    qp[(size_t)(4 * d + 3) << 10] = q.w;
    float t0 = q.x - v4[d].x; ls = fmaf(t0, t0, ls);
    float t1 = q.y - v4[d].y; ls = fmaf(t1, t1, ls);
    float t2 = q.z - v4[d].z; ls = fmaf(t2, t2, ls);
    float t3 = q.w - v4[d].w; ls = fmaf(t3, t3, ls);
  }
  red[tid] = ls;
  __syncthreads();
  for (int s = 64; s > 0; s >>= 1) {
    if (tid < s) red[tid] += red[tid + s];
    __syncthreads();
  }
  if (tid == 0) partial[blockIdx.x] = red[0];
}

__global__ __launch_bounds__(256) void loss_fin(
    const float* __restrict__ partial, float* __restrict__ out) {
  __shared__ float red[256];
  int t = threadIdx.x;
  red[t] = partial[t];
  __syncthreads();
  for (int s = 128; s > 0; s >>= 1) {
    if (t < s) red[t] += red[t + s];
    __syncthreads();
  }
  if (t == 0) out[0] = red[0] * (2.0f / 2097152.0f);
}

template<int CIN, int G, int ACT>
__global__ __launch_bounds__(256) void convT_t(
    const float* __restrict__ in, const float* __restrict__ wt,
    const float* __restrict__ bias, float* __restrict__ out,
    int Cout, int Hin, int Win) {
  const int Hout = Hin * 2, Wout = Win * 2;
  const int TW = Win >> 4;
  __shared__ float tile[18 * 19];
  int tid = threadIdx.x;
  int txl = tid & 15, tyl = tid >> 4;
  int tyt = blockIdx.x / TW, txt = blockIdx.x - tyt * TW;
  int ty0 = tyt << 4, tx0 = txt << 4;
  int og = blockIdx.y % (Cout / G);
  int b  = blockIdx.y / (Cout / G);
  int o0 = og * G;
  const int iy_org = ty0 - 1, ix_org = tx0 - 1;
  const float* ip = in + (size_t)b * CIN * Hin * Win;
  float a00[G], a01[G], a10[G], a11[G];
#pragma unroll
  for (int j = 0; j < G; ++j) {
    float bb = bias[o0 + j];
    a00[j] = bb; a01[j] = bb; a10[j] = bb; a11[j] = bb;
  }
  const int lb = tyl * 19 + txl;
  for (int i = 0; i < CIN; ++i) {
    const float* ic = ip + (size_t)i * Hin * Win;
    __syncthreads();
#pragma unroll
    for (int k = 0; k < 2; ++k) {
      int idx = tid + k * 256;
      if (idx < 18 * 18) {
        int r = idx / 18, c = idx - r * 18;
        int iy = iy_org + r, ix = ix_org + c;
        float v = ((unsigned)iy < (unsigned)Hin && (unsigned)ix < (unsigned)Win)
                      ? ic[(size_t)iy * Win + ix] : 0.0f;
        tile[r * 19 + c] = v;
      }
    }
    __syncthreads();
    float x00 = tile[lb],          x01 = tile[lb + 1],      x02 = tile[lb + 2];
    float x10 = tile[lb + 19],     x11 = tile[lb + 20],     x12 = tile[lb + 21];
    float x20 = tile[lb + 38],     x21 = tile[lb + 39],     x22 = tile[lb + 40];
    const float* wv = wt + ((size_t)i * Cout + o0) * 16;
#pragma unroll
    for (int j = 0; j < G; ++j) {
      const float* w4 = wv + j * 16;
      a00[j] = fmaf(x11, w4[5],  fmaf(x10, w4[7],  fmaf(x01, w4[13], fmaf(x00, w4[15], a00[j]))));
      a01[j] = fmaf(x12, w4[4],  fmaf(x11, w4[6],  fmaf(x02, w4[12], fmaf(x01, w4[14], a01[j]))));
      a10[j] = fmaf(x21, w4[1],  fmaf(x20, w4[3],  fmaf(x11, w4[9],  fmaf(x10, w4[11], a10[j]))));
      a11[j] = fmaf(x22, w4[0],  fmaf(x21, w4[2],  fmaf(x12, w4[8],  fmaf(x11, w4[10], a11[j]))));
    }
  }
  size_t cs = (size_t)Hout * Wout;
  int ty = ty0 + tyl, tx = tx0 + txl;
  size_t base = ((size_t)(b * Cout + o0) * Hout + 2 * (size_t)ty) * Wout + 2 * tx;
#pragma unroll
  for (int j = 0; j < G; ++j) {
    float v00 = a00[j], v01 = a01[j], v10 = a10[j], v11 = a11[j];
    if (ACT == 1) {
      v00 = fmaxf(v00, 0.0f); v01 = fmaxf(v01, 0.0f);
      v10 = fmaxf(v10, 0.0f); v11 = fmaxf(v11, 0.0f);
    } else if (ACT == 2) {
      v00 = 1.0f / (1.0f + expf(-v00)); v01 = 1.0f / (1.0f + expf(-v01));
      v10 = 1.0f / (1.0f + expf(-v10)); v11 = 1.0f / (1.0f + expf(-v11));
    }
    *(float2*)(out + base + (size_t)j * cs)        = make_float2(v00, v01);
    *(float2*)(out + base + (size_t)j * cs + Wout) = make_float2(v10, v11);
  }
}

extern "C" void kernel_launch(void* const* d_in, const int* in_sizes, int n_in,
                              void* d_out, int out_size, void* d_ws, size_t ws_size,
                              hipStream_t stream) {
  const float* x   = (const float*)d_in[0];
  const float* ew1 = (const float*)d_in[1];
  const float* eb1 = (const float*)d_in[2];
  const float* ew2 = (const float*)d_in[3];
  const float* eb2 = (const float*)d_in[4];
  const float* ew3 = (const float*)d_in[5];
  const float* eb3 = (const float*)d_in[6];
  const float* pw  = (const float*)d_in[7];
  const float* pb  = (const float*)d_in[8];
  const float* emb = (const float*)d_in[9];
  const float* dw1 = (const float*)d_in[10];
  const float* db1 = (const float*)d_in[11];
  const float* dw2 = (const float*)d_in[12];
  const float* db2 = (const float*)d_in[13];
  const float* dw3 = (const float*)d_in[14];
  const float* db3 = (const float*)d_in[15];
  float* out = (float*)d_out;
  char* ws = (char*)d_ws;

  // h1 split planes: 16 c8 x 130x130x16B, h + l.
  const size_t H1PLANE = 130ull * 130ull * 16ull;        // 270400
  const size_t H1LOFF  = 16ull * H1PLANE;                // 4326400
  const size_t SAI     = 2ull * H1LOFF;                  // 8652800
  // h2/d1 split planes: 32 c8 x 66x66x16B, h + l (shared layout + borders).
  const size_t H2PLANE = 66ull * 66ull * 16ull;          // 69696
  const size_t H2LOFF  = 32ull * H2PLANE;                // 2230272
  const size_t SBI     = 2ull * H2LOFF;                  // 4460544
  const size_t PER  = SAI + SBI + 2ull * 262144ull;      // 13637632
  const size_t WEXT = 4096ull + 13631488ull;
  int CB = 32;
  while (CB > 1 && (size_t)CB * PER + WEXT > ws_size) CB >>= 1;
  const size_t SA = (size_t)CB * SAI;
  const size_t SB = (size_t)CB * SBI;
  const size_t SC = (size_t)CB * 262144ull;
  float* A    = (float*)(ws);              // h1(split) -> h3(f32) -> d2(f32)
  float* Bp   = (float*)(ws + SA);         // h2(split) -> d1(split)
  float* ze   = (float*)(ws + SA + SB);
  float* zq   = (float*)(ws + SA + SB + SC);
  float* part = (float*)(ws + SA + SB + 2 * SC);
  _Float16* wh2  = (_Float16*)(ws + SA + SB + 2 * SC + 4096);
  _Float16* wl2  = wh2 + 524288;
  _Float16* wh3  = wl2 + 524288;
  _Float16* wl3  = wh3 + 2097152;
  _Float16* whT1 = wl3 + 2097152;
  _Float16* wlT1 = whT1 + 262144;
  _Float16* whT2 = wlT1 + 262144;
  _Float16* wlT2 = whT2 + 524288;

  wsplit_k<128><<<128, 256, 0, stream>>>(ew2, wh2, wl2, 256);
  wsplit_k<256><<<512, 256, 0, stream>>>(ew3, wh3, wl3, 512);
  wsplitT_k<64><<<64,  256, 0, stream>>>(dw1, whT1, wlT1, 256);
  wsplitT_k<256><<<128, 256, 0, stream>>>(dw2, whT2, wlT2, 128);

  for (int c0 = 0; c0 < 32; c0 += CB) {
    const float* xc = x + (size_t)c0 * 3 * 65536;
    float* outc = out + (size_t)c0 * 3 * 65536;
    // zero h1 + h2/d1 plane borders (interiors fully overwritten each pass)
    {
      int nb1 = 2 * 130 + 2 * 128;
      int tot1 = CB * 16 * 2 * nb1;
      border_k<<<(tot1 + 255) / 256, 256, 0, stream>>>(
          (char*)A, 16, 130, 130, SAI, H1LOFF, CB);
      int nb2 = 2 * 66 + 2 * 64;
      int tot2 = CB * 32 * 2 * nb2;
      border_k<<<(tot2 + 255) / 256, 256, 0, stream>>>(
          (char*)Bp, 32, 66, 66, SBI, H2LOFF, CB);
    }
    // encoder
    conv_t<3, 16, 1, 2><<<dim3(64, CB * 8), 256, 0, stream>>>(
        xc, ew1, eb1, A, 128, 256, 256, SAI, H1LOFF);
    conv_mfma2<128, 256, 1, 2, 1, 2, 1><<<dim3(128, CB), 256, 0, stream>>>(
        (const void*)A, wh2, wl2, eb2, Bp, 128, 128, SAI, H1LOFF, SBI, H2LOFF);
    conv_mfma2<256, 512, 2, 2, 1, 0, 1><<<dim3(32, CB * 2), 256, 0, stream>>>(
        (const void*)Bp, wh3, wl3, eb3, A, 64, 64, SBI, H2LOFF, 0, 0);
    conv1x1_k<512, 4><<<dim3(4, CB * 16), 256, 0, stream>>>(A, pw, pb, ze, 64, 1024);
    vq_k<<<CB * 8, 128, 0, stream>>>(ze, emb, zq, part + (size_t)c0 * 8);
    // decoder: convT1 f32-in -> d1 split planes; convT2 DMA-staged -> d2 f32
    convT_mfma<64, 256, 4, 1, 0, 2, 1><<<dim3(32, CB * 4), 256, 0, stream>>>(
        (const void*)zq, whT1, wlT1, db1, Bp, 32, 32, 0, 0, SBI, H2LOFF);
    convT_mfma<256, 128, 2, 1, 2, 0, 1><<<dim3(128, CB * 2), 256, 0, stream>>>(
        (const void*)Bp, whT2, wlT2, db2, A, 64, 64, SBI, H2LOFF, 0, 0);
    convT_t<128, 3, 2><<<dim3(64, CB * 1), 256, 0, stream>>>(A, dw3, db3, outc, 3, 128, 128);
  }
  loss_fin<<<1, 256, 0, stream>>>(part, out + (size_t)(out_size - 1));
}

// Round 15
// 2182.596 us; speedup vs baseline: 1.3274x; 1.3274x over previous
//
#include <hip/hip_runtime.h>
#include <cstddef>
#include <cstdint>

typedef __attribute__((ext_vector_type(8))) _Float16 half8;
typedef __attribute__((ext_vector_type(4))) _Float16 half4;
typedef __attribute__((ext_vector_type(4))) float f32x4;

static __device__ __forceinline__ unsigned packhl(float v) {
  _Float16 h = (_Float16)v;
  _Float16 l = (_Float16)((v - (float)h) * 2048.0f);
  return (unsigned)__builtin_bit_cast(unsigned short, h) |
         ((unsigned)__builtin_bit_cast(unsigned short, l) << 16);
}

// ---------------------------------------------------------------------------
// VQ-VAE forward. R15 = R13 structure (best, 2431us) + decoder convT uses
// f16 h-only MFMA (SPLITX=0; 1 MFMA/tap instead of 3). Encoder keeps the full
// 2-term split (argmin/loss bit-identical to R5-R13). Decoder output noise
// ~1e-3..1e-2, within absmax threshold 2.97e-2.
// ---------------------------------------------------------------------------

// Pre-split conv weights: W[Cout][CIN][4][4] -> [tap][cb][k8][cout][8] f16 h/l
template<int CIN>
__global__ __launch_bounds__(256) void wsplit_k(
    const float* __restrict__ W, _Float16* __restrict__ Wh,
    _Float16* __restrict__ Wl, int Cout) {
  constexpr int NCB = CIN / 32;
  int idx = blockIdx.x * 256 + threadIdx.x;
  if (idx >= Cout * CIN) return;
  int ci = idx % CIN, co = idx / CIN;
  int cb = ci >> 5, k8 = (ci >> 3) & 3, j = ci & 7;
  const float* wp = W + (size_t)idx * 16;
#pragma unroll
  for (int tap = 0; tap < 16; ++tap) {
    float w = wp[tap];
    _Float16 wh = (_Float16)w;
    _Float16 wl = (_Float16)((w - (float)wh) * 2048.0f);
    size_t o = (((size_t)(tap * NCB + cb) * 4 + k8) * Cout + co) * 8 + j;
    Wh[o] = wh; Wl[o] = wl;
  }
}

// Pre-split convT weights: W[CIN][Cout][4][4] -> [t][cb][k8][cout][8] f16 h/l
template<int CIN>
__global__ __launch_bounds__(256) void wsplitT_k(
    const float* __restrict__ W, _Float16* __restrict__ Wh,
    _Float16* __restrict__ Wl, int Cout) {
  constexpr int NCB = CIN / 32;
  int idx = blockIdx.x * 256 + threadIdx.x;
  if (idx >= CIN * Cout) return;
  int co = idx % Cout, ci = idx / Cout;
  int cb = ci >> 5, k8 = (ci >> 3) & 3, j = ci & 7;
  const float* wp = W + (size_t)idx * 16;
#pragma unroll
  for (int t = 0; t < 16; ++t) {
    int py = (t >> 3) & 1, px = (t >> 2) & 1, i0 = (t >> 1) & 1, i1 = t & 1;
    int kh = py ? (i0 ? 2 : 0) : (i0 ? 3 : 1);
    int kw = px ? (i1 ? 2 : 0) : (i1 ? 3 : 1);
    float w = wp[kh * 4 + kw];
    _Float16 wh = (_Float16)w;
    _Float16 wl = (_Float16)((w - (float)wh) * 2048.0f);
    size_t o = (((size_t)(t * NCB + cb) * 4 + k8) * Cout + co) * 8 + j;
    Wh[o] = wh; Wl[o] = wl;
  }
}

// Zero the 1-px border of split h/l planes. H2/W2 = padded dims.
__global__ __launch_bounds__(256) void border_k(
    char* base, int c8n, int H2, int W2, size_t SAI, size_t LOFF, int nimg) {
  int nb = 2 * W2 + 2 * (H2 - 2);
  int tot = nimg * c8n * 2 * nb;
  int idx = blockIdx.x * 256 + threadIdx.x;
  if (idx >= tot) return;
  int s = idx % nb; int r = idx / nb;
  int pl = r & 1; r >>= 1;
  int c8 = r % c8n; int b = r / c8n;
  int y, x;
  if (s < W2)            { y = 0;       x = s; }
  else if (s < 2 * W2)   { y = H2 - 1;  x = s - W2; }
  else { int t = s - 2 * W2; y = 1 + (t >> 1); x = (t & 1) ? W2 - 1 : 0; }
  size_t PLANE = (size_t)H2 * W2 * 16;
  char* p = base + (size_t)b * SAI + (size_t)pl * LOFF + (size_t)c8 * PLANE
            + ((size_t)y * W2 + x) * 16;
  *(uint4*)p = make_uint4(0, 0, 0, 0);
}

// MFMA conv k4 s2 p1 (+ReLU). Split-plane input staged via global_load_lds.
// PACKOUT: 0 = f32 NCHW, 2 = split h/l planes (+border).   (R13-verified)
template<int CIN, int COUT, int CGRP, int NF, int RELU, int PACKOUT>
__global__ __launch_bounds__(256) void conv_mfma2(
    const void* __restrict__ inP, const _Float16* __restrict__ Whg,
    const _Float16* __restrict__ Wlg, const float* __restrict__ bias,
    float* __restrict__ out, int Hin, int Win,
    size_t inSAI, size_t inLOFF, size_t outSAI, size_t outLOFF) {
  constexpr int NCB  = CIN / 32;
  constexpr int MT   = COUT / CGRP;
  constexpr int MF   = MT / 64;
  constexpr int ROWS = 2 * NF + 2;
  constexpr int NPOS = ROWS * 34;
  constexpr int K8S  = NPOS + 6;
  const int Hout = Hin >> 1, Wout = Win >> 1;
  const int TW = Wout >> 4;
  __shared__ half8 Bh[4 * K8S], Bl[4 * K8S];
  const int tid = threadIdx.x;
  const int lane = tid & 63, w = tid >> 6;
  const int l15 = lane & 15, k8 = lane >> 4;
  int tx, ty, cg, b;
  {
    unsigned nwg = gridDim.x * gridDim.y;
    unsigned id  = blockIdx.y * gridDim.x + blockIdx.x;
    unsigned sw  = (id & 7) * (nwg >> 3) + (id >> 3);
    const int bx = sw % gridDim.x, by = sw / gridDim.x;
    tx = bx % TW; ty = bx / TW;
    cg = by % CGRP;
    b  = by / CGRP;
  }
  const int oy0 = ty * NF, ox0 = tx << 4;
  const int iy_org = 2 * oy0 - 1, ix_org = 2 * ox0 - 1;
  const int cbase = cg * MT + w * (MT / 4);
  const size_t tapStride = (size_t)NCB * 4 * COUT * 8;

  unsigned goff[4];
  const char* baseh;
  size_t PLANE;
  {
    const int W2 = Win + 2;
    PLANE = (size_t)(Hin + 2) * W2 * 16;
    constexpr int S0[4] = {0, 64, 128, NPOS - 64};
#pragma unroll
    for (int t = 0; t < 4; ++t) {
      int s = S0[t] + lane;
      int r = s / 17, c = s - r * 17;
      int hy = r >> 1, p = r & 1;
      int hx = (c << 1) | p;
      int iy = iy_org + hy + 1, ix = ix_org + hx + 1;
      goff[t] = (unsigned)(((size_t)iy * W2 + ix) * 16);
    }
    baseh = (const char*)inP + ((size_t)b * inSAI) + (size_t)w * PLANE;
  }

  f32x4 accM[MF][NF], accX[MF][NF];
#pragma unroll
  for (int m = 0; m < MF; ++m)
#pragma unroll
    for (int nf = 0; nf < NF; ++nf) {
      accM[m][nf] = f32x4{0,0,0,0};
      accX[m][nf] = f32x4{0,0,0,0};
    }

  for (int cb = 0; cb < NCB; ++cb) {
    __syncthreads();
    {
      const char* pc = baseh + (size_t)cb * 4 * PLANE;
      char* lh = (char*)&Bh[w * K8S];
      char* ll = (char*)&Bl[w * K8S];
      constexpr int S0[4] = {0, 64, 128, NPOS - 64};
#pragma unroll
      for (int t = 0; t < 4; ++t) {
        __builtin_amdgcn_global_load_lds(
            (const __attribute__((address_space(1))) void*)(pc + goff[t]),
            (__attribute__((address_space(3))) void*)(lh + S0[t] * 16), 16, 0, 0);
        __builtin_amdgcn_global_load_lds(
            (const __attribute__((address_space(1))) void*)(pc + inLOFF + goff[t]),
            (__attribute__((address_space(3))) void*)(ll + S0[t] * 16), 16, 0, 0);
      }
    }
    __syncthreads();
    const _Float16* aph = Whg + (((size_t)cb * 4 + k8) * COUT + cbase + l15) * 8;
    const _Float16* apl = Wlg + (((size_t)cb * 4 + k8) * COUT + cbase + l15) * 8;
    half8 ah[2][MF], al[2][MF];
#pragma unroll
    for (int m = 0; m < MF; ++m) {
      ah[0][m] = *(const half8*)(aph + m * 128);
      al[0][m] = *(const half8*)(apl + m * 128);
    }
#pragma unroll
    for (int tp = 0; tp < 16; ++tp) {
      const int cur = tp & 1, nxt = cur ^ 1;
      if (tp < 15) {
#pragma unroll
        for (int m = 0; m < MF; ++m) {
          ah[nxt][m] = *(const half8*)(aph + (size_t)(tp + 1) * tapStride + m * 128);
          al[nxt][m] = *(const half8*)(apl + (size_t)(tp + 1) * tapStride + m * 128);
        }
      }
      const int kh = tp >> 2, kw = tp & 3;
      const int p = kw & 1, cidx = kw >> 1;
#pragma unroll
      for (int nf = 0; nf < NF; ++nf) {
        const int slot = k8 * K8S + ((2 * nf + kh) * 2 + p) * 17 + l15 + cidx;
        const half8 bh = Bh[slot], bl = Bl[slot];
#pragma unroll
        for (int m = 0; m < MF; ++m) {
          accM[m][nf] = __builtin_amdgcn_mfma_f32_16x16x32_f16(ah[cur][m], bh, accM[m][nf], 0, 0, 0);
          accX[m][nf] = __builtin_amdgcn_mfma_f32_16x16x32_f16(ah[cur][m], bl, accX[m][nf], 0, 0, 0);
          accX[m][nf] = __builtin_amdgcn_mfma_f32_16x16x32_f16(al[cur][m], bh, accX[m][nf], 0, 0, 0);
        }
      }
    }
  }
  // ---- epilogue ----
#pragma unroll
  for (int m = 0; m < MF; ++m)
#pragma unroll
    for (int nf = 0; nf < NF; ++nf) {
      int oy = oy0 + nf, ox = ox0 + l15;
      if (PACKOUT == 2) {
        const int W2o = Wout + 2;
        const size_t PLANEo = (size_t)(Hout + 2) * W2o * 16;
        half4 hv, lv;
#pragma unroll
        for (int i = 0; i < 4; ++i) {
          int co = cbase + m * 16 + k8 * 4 + i;
          float v = accM[m][nf][i] + accX[m][nf][i] * (1.0f / 2048.0f) + bias[co];
          if (RELU) v = fmaxf(v, 0.0f);
          _Float16 h = (_Float16)v;
          hv[i] = h; lv[i] = (_Float16)((v - (float)h) * 2048.0f);
        }
        int c8 = (cbase + m * 16 + k8 * 4) >> 3;
        int j0 = (k8 & 1) * 4;
        char* ob = (char*)out + (size_t)b * outSAI + (size_t)c8 * PLANEo
                   + (((size_t)(oy + 1) * W2o) + ox + 1) * 16 + j0 * 2;
        *(half4*)ob = hv;
        *(half4*)(ob + outLOFF) = lv;
      } else {
#pragma unroll
        for (int i = 0; i < 4; ++i) {
          int co = cbase + m * 16 + k8 * 4 + i;
          float v = accM[m][nf][i] + accX[m][nf][i] * (1.0f / 2048.0f) + bias[co];
          if (RELU) v = fmaxf(v, 0.0f);
          out[(((size_t)b * COUT + co) * Hout + oy) * Wout + ox] = v;
        }
      }
    }
}

// MFMA convT k4 s2 p1 (+ReLU). Parity decomposition (R13 shape).
// PACKIN: 0 = f32 NCHW, 1 = packed u32 interleave.
// PACKOUT: 0 = f32 NCHW, 1 = packed u32 interleave.
// SPLITX: 1 = full 2-term split (3 MFMA/tap); 0 = f16 h-only (1 MFMA/tap).
template<int CIN, int COUT, int CGRP, int RELU, int PACKIN, int PACKOUT,
         int SWZ, int SPLITX>
__global__ __launch_bounds__(256) void convT_mfma(
    const float* __restrict__ in, const _Float16* __restrict__ Whg,
    const _Float16* __restrict__ Wlg, const float* __restrict__ bias,
    float* __restrict__ out, int Hin, int Win) {
  constexpr int NCB = CIN / 32;
  constexpr int MT  = COUT / CGRP;
  constexpr int MF  = MT / 64;
  const int Hout = Hin * 2, Wout = Win * 2;
  const int TW = Win >> 4;
  __shared__ half8 Bh[4 * 72];
  __shared__ half8 Bl[SPLITX ? 4 * 72 : 1];
  const int tid = threadIdx.x;
  const int lane = tid & 63, w = tid >> 6;
  const int l15 = lane & 15, k8 = lane >> 4;
  int bx = blockIdx.x, by = blockIdx.y;
  if (SWZ) {
    unsigned nwg = gridDim.x * gridDim.y;
    unsigned id  = (unsigned)by * gridDim.x + bx;
    unsigned sw  = (id & 7) * (nwg >> 3) + (id >> 3);
    bx = (int)(sw % gridDim.x); by = (int)(sw / gridDim.x);
  }
  const int tx = bx % TW, ty = bx / TW;
  const int cg = by % CGRP;
  const int b  = by / CGRP;
  const int ty0 = ty << 1, tx0 = tx << 4;
  const int cbase = cg * MT + w * (MT / 4);
  const size_t HW = (size_t)Hin * Win;
  const size_t tapStride = (size_t)NCB * 4 * COUT * 8;

  f32x4 accM[MF][4][2], accX[SPLITX ? MF : 1][4][2];
#pragma unroll
  for (int m = 0; m < MF; ++m)
#pragma unroll
    for (int p = 0; p < 4; ++p)
#pragma unroll
      for (int nf = 0; nf < 2; ++nf) {
        accM[m][p][nf] = f32x4{0,0,0,0};
        if (SPLITX) accX[m][p][nf] = f32x4{0,0,0,0};
      }

  for (int cb = 0; cb < NCB; ++cb) {
    __syncthreads();
    for (int u = tid; u < 288; u += 256) {
      int pos = u % 72, kk = u / 72;
      int r = pos / 18, c = pos - r * 18;
      int iy = ty0 - 1 + r, ix = tx0 - 1 + c;
      bool ok = (unsigned)iy < (unsigned)Hin && (unsigned)ix < (unsigned)Win;
      half8 vh, vl;
      if (PACKIN) {
        uint4 qa = {0,0,0,0}, qb = {0,0,0,0};
        if (ok) {
          const uint4* gp = (const uint4*)((const unsigned*)in +
              (((size_t)b * (CIN / 8) + cb * 4 + kk) * HW + (size_t)iy * Win + ix) * 8);
          qa = gp[0]; qb = gp[1];
        }
        unsigned av[8] = {qa.x, qa.y, qa.z, qa.w, qb.x, qb.y, qb.z, qb.w};
#pragma unroll
        for (int j = 0; j < 8; ++j) {
          vh[j] = __builtin_bit_cast(_Float16, (unsigned short)(av[j] & 0xffffu));
          if (SPLITX)
            vl[j] = __builtin_bit_cast(_Float16, (unsigned short)(av[j] >> 16));
        }
      } else {
        const float* gp = in + ((size_t)b * CIN + cb * 32 + kk * 8) * HW
                          + (ptrdiff_t)iy * Win + ix;
#pragma unroll
        for (int j = 0; j < 8; ++j) {
          float x = ok ? gp[(size_t)j * HW] : 0.0f;
          _Float16 xh = (_Float16)x;
          vh[j] = xh;
          if (SPLITX) vl[j] = (_Float16)((x - (float)xh) * 2048.0f);
        }
      }
      Bh[kk * 72 + pos] = vh;
      if (SPLITX) Bl[kk * 72 + pos] = vl;
    }
    __syncthreads();
    const _Float16* aph = Whg + (((size_t)cb * 4 + k8) * COUT + cbase + l15) * 8;
    const _Float16* apl = Wlg + (((size_t)cb * 4 + k8) * COUT + cbase + l15) * 8;
    half8 ah[2][MF], al[2][MF];
#pragma unroll
    for (int m = 0; m < MF; ++m) {
      ah[0][m] = *(const half8*)(aph + m * 128);
      if (SPLITX) al[0][m] = *(const half8*)(apl + m * 128);
    }
#pragma unroll
    for (int t = 0; t < 16; ++t) {
      const int cur = t & 1, nxt = cur ^ 1;
      if (t < 15) {
#pragma unroll
        for (int m = 0; m < MF; ++m) {
          ah[nxt][m] = *(const half8*)(aph + (size_t)(t + 1) * tapStride + m * 128);
          if (SPLITX)
            al[nxt][m] = *(const half8*)(apl + (size_t)(t + 1) * tapStride + m * 128);
        }
      }
      const int py = (t >> 3) & 1, px = (t >> 2) & 1;
      const int i0 = (t >> 1) & 1, i1 = t & 1;
      const int dy = py ? (i0 ? 0 : 1) : (i0 ? -1 : 0);
      const int dx = px ? (i1 ? 0 : 1) : (i1 ? -1 : 0);
      const int p = py * 2 + px;
#pragma unroll
      for (int nf = 0; nf < 2; ++nf) {
        int slot = k8 * 72 + (nf + 1 + dy) * 18 + (l15 + 1 + dx);
        half8 bh = Bh[slot];
#pragma unroll
        for (int m = 0; m < MF; ++m) {
          accM[m][p][nf] = __builtin_amdgcn_mfma_f32_16x16x32_f16(ah[cur][m], bh, accM[m][p][nf], 0, 0, 0);
          if (SPLITX) {
            half8 bl = Bl[slot];
            accX[m][p][nf] = __builtin_amdgcn_mfma_f32_16x16x32_f16(ah[cur][m], bl, accX[m][p][nf], 0, 0, 0);
            accX[m][p][nf] = __builtin_amdgcn_mfma_f32_16x16x32_f16(al[cur][m], bh, accX[m][p][nf], 0, 0, 0);
          }
        }
      }
    }
  }
#pragma unroll
  for (int m = 0; m < MF; ++m) {
    const int co0m = cbase + m * 16;
#pragma unroll
    for (int nf = 0; nf < 2; ++nf) {
#pragma unroll
      for (int i = 0; i < 4; ++i) {
        int co = co0m + k8 * 4 + i;
        float bb = bias[co];
#pragma unroll
        for (int py = 0; py < 2; ++py) {
          float v0, v1;
          if (SPLITX) {
            v0 = accM[m][py * 2 + 0][nf][i] + accX[m][py * 2 + 0][nf][i] * (1.0f / 2048.0f) + bb;
            v1 = accM[m][py * 2 + 1][nf][i] + accX[m][py * 2 + 1][nf][i] * (1.0f / 2048.0f) + bb;
          } else {
            v0 = accM[m][py * 2 + 0][nf][i] + bb;
            v1 = accM[m][py * 2 + 1][nf][i] + bb;
          }
          if (RELU) { v0 = fmaxf(v0, 0.0f); v1 = fmaxf(v1, 0.0f); }
          int oy = 2 * (ty0 + nf) + py, ox = 2 * (tx0 + l15);
          if (PACKOUT) {
            unsigned* outU = (unsigned*)out;
            int co8 = (co0m >> 3) + (k8 >> 1);
            int j = (k8 * 4 + i) & 7;
            size_t base = ((size_t)b * (COUT / 8) + co8) * ((size_t)Hout * Wout);
            outU[(base + (size_t)oy * Wout + ox) * 8 + j]     = packhl(v0);
            outU[(base + (size_t)oy * Wout + ox + 1) * 8 + j] = packhl(v1);
          } else {
            *(float2*)(out + (((size_t)b * COUT + co) * Hout + oy) * Wout + ox) =
                make_float2(v0, v1);
          }
        }
      }
    }
  }
}

// ---------------- f32 kernels ----------------------------------------------

template<int CIN, int G, int RELU, int PACKOUT>
__global__ __launch_bounds__(256) void conv_t(
    const float* __restrict__ in, const float* __restrict__ wt,
    const float* __restrict__ bias, float* __restrict__ out,
    int Cout, int Hin, int Win, size_t oSAI, size_t oLOFF) {
  const int Hout = Hin >> 1, Wout = Win >> 1;
  const int TW = Wout >> 4;
  __shared__ float tile[34 * 35];
  int tid = threadIdx.x;
  int oxl = tid & 15, oyl = tid >> 4;
  int tyt = blockIdx.x / TW, txt = blockIdx.x - tyt * TW;
  int oy0 = tyt << 4, ox0 = txt << 4;
  int cg = blockIdx.y % (Cout / G);
  int b  = blockIdx.y / (Cout / G);
  int co0 = cg * G;
  const int iy_org = 2 * oy0 - 1, ix_org = 2 * ox0 - 1;
  const float* ip = in + (size_t)b * CIN * Hin * Win;
  float acc[G];
#pragma unroll
  for (int j = 0; j < G; ++j) acc[j] = bias[co0 + j];
  const int lbase = (2 * oyl) * 35 + 2 * oxl;
  for (int ci = 0; ci < CIN; ++ci) {
    const float* ic = ip + (size_t)ci * Hin * Win;
    __syncthreads();
#pragma unroll
    for (int k = 0; k < 5; ++k) {
      int idx = tid + k * 256;
      if (idx < 34 * 34) {
        int r = idx / 34, c = idx - r * 34;
        int iy = iy_org + r, ix = ix_org + c;
        float v = ((unsigned)iy < (unsigned)Hin && (unsigned)ix < (unsigned)Win)
                      ? ic[(size_t)iy * Win + ix] : 0.0f;
        tile[r * 35 + c] = v;
      }
    }
    __syncthreads();
    float xv[16];
#pragma unroll
    for (int kh = 0; kh < 4; ++kh)
#pragma unroll
      for (int kw = 0; kw < 4; ++kw)
        xv[kh * 4 + kw] = tile[lbase + kh * 35 + kw];
    const float* wc = wt + ((size_t)co0 * CIN + ci) * 16;
#pragma unroll
    for (int j = 0; j < G; ++j) {
      const float* wj = wc + (size_t)j * CIN * 16;
#pragma unroll
      for (int t2 = 0; t2 < 16; ++t2) acc[j] = fmaf(xv[t2], wj[t2], acc[j]);
    }
  }
  int oy = oy0 + oyl, ox = ox0 + oxl;
  if (RELU) {
#pragma unroll
    for (int j = 0; j < G; ++j) acc[j] = fmaxf(acc[j], 0.0f);
  }
  if (PACKOUT == 2) {
    const int W2 = Wout + 2;
    const size_t PLANE = (size_t)(Hout + 2) * W2 * 16;
    char* ob0 = (char*)out + (size_t)b * oSAI
                + ((size_t)(oy + 1) * W2 + ox + 1) * 16;
#pragma unroll
    for (int mb = 0; mb < G / 8; ++mb) {
      half8 hv, lv;
#pragma unroll
      for (int j = 0; j < 8; ++j) {
        float v = acc[mb * 8 + j];
        _Float16 h = (_Float16)v;
        hv[j] = h; lv[j] = (_Float16)((v - (float)h) * 2048.0f);
      }
      char* ob = ob0 + (size_t)((co0 >> 3) + mb) * PLANE;
      *(half8*)ob = hv;
      *(half8*)(ob + oLOFF) = lv;
    }
  } else {
    size_t cs = (size_t)Hout * Wout;
    float* op = out + ((size_t)(b * Cout + co0) * Hout + oy) * Wout + ox;
#pragma unroll
    for (int j = 0; j < G; ++j) op[(size_t)j * cs] = acc[j];
  }
}

template<int CIN, int G>
__global__ __launch_bounds__(256) void conv1x1_k(
    const float* __restrict__ in, const float* __restrict__ wt,
    const float* __restrict__ bias, float* __restrict__ out,
    int Cout, int HW) {
  int hw = blockIdx.x * 256 + threadIdx.x;
  int cg = blockIdx.y % (Cout / G);
  int b  = blockIdx.y / (Cout / G);
  int co0 = cg * G;
  const float* ip = in + (size_t)b * CIN * HW + hw;
  float acc[G];
#pragma unroll
  for (int j = 0; j < G; ++j) acc[j] = bias[co0 + j];
#pragma unroll 4
  for (int ci = 0; ci < CIN; ++ci) {
    float xv = ip[(size_t)ci * HW];
#pragma unroll
    for (int j = 0; j < G; ++j)
      acc[j] = fmaf(xv, wt[(size_t)(co0 + j) * CIN + ci], acc[j]);
  }
  float* op = out + ((size_t)(b * Cout + co0)) * HW + hw;
#pragma unroll
  for (int j = 0; j < G; ++j) op[(size_t)j * HW] = acc[j];
}

__global__ __launch_bounds__(128) void vq_k(
    const float* __restrict__ ze, const float* __restrict__ emb,
    float* __restrict__ zq, float* __restrict__ partial) {
  __shared__ float4 se4[128 * 16];
  __shared__ float red[128];
  int tid = threadIdx.x;
  int gid = blockIdx.x * 128 + tid;
  int b = gid >> 10, n = gid & 1023;
  const float* zp = ze + ((size_t)b << 16) + n;
  float4 v4[16];
#pragma unroll
  for (int d = 0; d < 16; ++d) {
    v4[d].x = zp[(size_t)(4 * d + 0) << 10];
    v4[d].y = zp[(size_t)(4 * d + 1) << 10];
    v4[d].z = zp[(size_t)(4 * d + 2) << 10];
    v4[d].w = zp[(size_t)(4 * d + 3) << 10];
  }
  float best = 1e30f; int bi = 0;
  for (int c = 0; c < 4; ++c) {
    __syncthreads();
    for (int i = tid; i < 2048; i += 128)
      se4[i] = ((const float4*)emb)[(c << 11) + i];
    __syncthreads();
    for (int k = 0; k < 128; ++k) {
      const float4* e = se4 + (k << 4);
      float s = 0.0f;
#pragma unroll
      for (int d = 0; d < 16; ++d) {
        float4 ev = e[d];
        float t0 = v4[d].x - ev.x; s = fmaf(t0, t0, s);
        float t1 = v4[d].y - ev.y; s = fmaf(t1, t1, s);
        float t2 = v4[d].z - ev.z; s = fmaf(t2, t2, s);
        float t3 = v4[d].w - ev.w; s = fmaf(t3, t3, s);
      }
      if (s < best) { best = s; bi = (c << 7) + k; }
    }
  }
  const float4* eb4 = (const float4*)emb + ((size_t)bi << 4);
  float* qp = zq + ((size_t)b << 16) + n;
  float ls = 0.0f;
#pragma unroll
  for (int d = 0; d < 16; ++d) {
    float4 q = eb4[d];
    qp[(size_t)(4 * d + 0) << 10] = q.x;
    qp[(size_t)(4 * d + 1) << 10] = q.y;
    qp[(size_t)(4 * d + 2) << 10] = q.z;
    qp[(size_t)(4 * d + 3) << 10] = q.w;
    float t0 = q.x - v4[d].x; ls = fmaf(t0, t0, ls);
    float t1 = q.y - v4[d].y; ls = fmaf(t1, t1, ls);
    float t2 = q.z - v4[d].z; ls = fmaf(t2, t2, ls);
    float t3 = q.w - v4[d].w; ls = fmaf(t3, t3, ls);
  }
  red[tid] = ls;
  __syncthreads();
  for (int s = 64; s > 0; s >>= 1) {
    if (tid < s) red[tid] += red[tid + s];
    __syncthreads();
  }
  if (tid == 0) partial[blockIdx.x] = red[0];
}

__global__ __launch_bounds__(256) void loss_fin(
    const float* __restrict__ partial, float* __restrict__ out) {
  __shared__ float red[256];
  int t = threadIdx.x;
  red[t] = partial[t];
  __syncthreads();
  for (int s = 128; s > 0; s >>= 1) {
    if (t < s) red[t] += red[t + s];
    __syncthreads();
  }
  if (t == 0) out[0] = red[0] * (2.0f / 2097152.0f);
}

template<int CIN, int G, int ACT>
__global__ __launch_bounds__(256) void convT_t(
    const float* __restrict__ in, const float* __restrict__ wt,
    const float* __restrict__ bias, float* __restrict__ out,
    int Cout, int Hin, int Win) {
  const int Hout = Hin * 2, Wout = Win * 2;
  const int TW = Win >> 4;
  __shared__ float tile[18 * 19];
  int tid = threadIdx.x;
  int txl = tid & 15, tyl = tid >> 4;
  int tyt = blockIdx.x / TW, txt = blockIdx.x - tyt * TW;
  int ty0 = tyt << 4, tx0 = txt << 4;
  int og = blockIdx.y % (Cout / G);
  int b  = blockIdx.y / (Cout / G);
  int o0 = og * G;
  const int iy_org = ty0 - 1, ix_org = tx0 - 1;
  const float* ip = in + (size_t)b * CIN * Hin * Win;
  float a00[G], a01[G], a10[G], a11[G];
#pragma unroll
  for (int j = 0; j < G; ++j) {
    float bb = bias[o0 + j];
    a00[j] = bb; a01[j] = bb; a10[j] = bb; a11[j] = bb;
  }
  const int lb = tyl * 19 + txl;
  for (int i = 0; i < CIN; ++i) {
    const float* ic = ip + (size_t)i * Hin * Win;
    __syncthreads();
#pragma unroll
    for (int k = 0; k < 2; ++k) {
      int idx = tid + k * 256;
      if (idx < 18 * 18) {
        int r = idx / 18, c = idx - r * 18;
        int iy = iy_org + r, ix = ix_org + c;
        float v = ((unsigned)iy < (unsigned)Hin && (unsigned)ix < (unsigned)Win)
                      ? ic[(size_t)iy * Win + ix] : 0.0f;
        tile[r * 19 + c] = v;
      }
    }
    __syncthreads();
    float x00 = tile[lb],          x01 = tile[lb + 1],      x02 = tile[lb + 2];
    float x10 = tile[lb + 19],     x11 = tile[lb + 20],     x12 = tile[lb + 21];
    float x20 = tile[lb + 38],     x21 = tile[lb + 39],     x22 = tile[lb + 40];
    const float* wv = wt + ((size_t)i * Cout + o0) * 16;
#pragma unroll
    for (int j = 0; j < G; ++j) {
      const float* w4 = wv + j * 16;
      a00[j] = fmaf(x11, w4[5],  fmaf(x10, w4[7],  fmaf(x01, w4[13], fmaf(x00, w4[15], a00[j]))));
      a01[j] = fmaf(x12, w4[4],  fmaf(x11, w4[6],  fmaf(x02, w4[12], fmaf(x01, w4[14], a01[j]))));
      a10[j] = fmaf(x21, w4[1],  fmaf(x20, w4[3],  fmaf(x11, w4[9],  fmaf(x10, w4[11], a10[j]))));
      a11[j] = fmaf(x22, w4[0],  fmaf(x21, w4[2],  fmaf(x12, w4[8],  fmaf(x11, w4[10], a11[j]))));
    }
  }
  size_t cs = (size_t)Hout * Wout;
  int ty = ty0 + tyl, tx = tx0 + txl;
  size_t base = ((size_t)(b * Cout + o0) * Hout + 2 * (size_t)ty) * Wout + 2 * tx;
#pragma unroll
  for (int j = 0; j < G; ++j) {
    float v00 = a00[j], v01 = a01[j], v10 = a10[j], v11 = a11[j];
    if (ACT == 1) {
      v00 = fmaxf(v00, 0.0f); v01 = fmaxf(v01, 0.0f);
      v10 = fmaxf(v10, 0.0f); v11 = fmaxf(v11, 0.0f);
    } else if (ACT == 2) {
      v00 = 1.0f / (1.0f + expf(-v00)); v01 = 1.0f / (1.0f + expf(-v01));
      v10 = 1.0f / (1.0f + expf(-v10)); v11 = 1.0f / (1.0f + expf(-v11));
    }
    *(float2*)(out + base + (size_t)j * cs)        = make_float2(v00, v01);
    *(float2*)(out + base + (size_t)j * cs + Wout) = make_float2(v10, v11);
  }
}

extern "C" void kernel_launch(void* const* d_in, const int* in_sizes, int n_in,
                              void* d_out, int out_size, void* d_ws, size_t ws_size,
                              hipStream_t stream) {
  const float* x   = (const float*)d_in[0];
  const float* ew1 = (const float*)d_in[1];
  const float* eb1 = (const float*)d_in[2];
  const float* ew2 = (const float*)d_in[3];
  const float* eb2 = (const float*)d_in[4];
  const float* ew3 = (const float*)d_in[5];
  const float* eb3 = (const float*)d_in[6];
  const float* pw  = (const float*)d_in[7];
  const float* pb  = (const float*)d_in[8];
  const float* emb = (const float*)d_in[9];
  const float* dw1 = (const float*)d_in[10];
  const float* db1 = (const float*)d_in[11];
  const float* dw2 = (const float*)d_in[12];
  const float* db2 = (const float*)d_in[13];
  const float* dw3 = (const float*)d_in[14];
  const float* db3 = (const float*)d_in[15];
  float* out = (float*)d_out;
  char* ws = (char*)d_ws;

  // h1 split planes: 16 c8 x 130x130x16B, h + l.
  const size_t H1PLANE = 130ull * 130ull * 16ull;        // 270400
  const size_t H1LOFF  = 16ull * H1PLANE;                // 4326400
  const size_t SAI     = 2ull * H1LOFF;                  // 8652800
  // h2 split planes: 32 c8 x 66x66x16B, h + l (d1 packed u32 aliases region).
  const size_t H2PLANE = 66ull * 66ull * 16ull;          // 69696
  const size_t H2LOFF  = 32ull * H2PLANE;                // 2230272
  const size_t SBI     = 2ull * H2LOFF;                  // 4460544
  const size_t PER  = SAI + SBI + 2ull * 262144ull;      // 13637632
  const size_t WEXT = 4096ull + 13631488ull;
  int CB = 32;
  while (CB > 1 && (size_t)CB * PER + WEXT > ws_size) CB >>= 1;
  const size_t SA = (size_t)CB * SAI;
  const size_t SB = (size_t)CB * SBI;
  const size_t SC = (size_t)CB * 262144ull;
  float* A    = (float*)(ws);              // h1(split) -> h3(f32) -> d2(f32)
  float* Bp   = (float*)(ws + SA);         // h2(split) -> d1(packed)
  float* ze   = (float*)(ws + SA + SB);
  float* zq   = (float*)(ws + SA + SB + SC);
  float* part = (float*)(ws + SA + SB + 2 * SC);
  _Float16* wh2  = (_Float16*)(ws + SA + SB + 2 * SC + 4096);
  _Float16* wl2  = wh2 + 524288;
  _Float16* wh3  = wl2 + 524288;
  _Float16* wl3  = wh3 + 2097152;
  _Float16* whT1 = wl3 + 2097152;
  _Float16* wlT1 = whT1 + 262144;
  _Float16* whT2 = wlT1 + 262144;
  _Float16* wlT2 = whT2 + 524288;

  wsplit_k<128><<<128, 256, 0, stream>>>(ew2, wh2, wl2, 256);
  wsplit_k<256><<<512, 256, 0, stream>>>(ew3, wh3, wl3, 512);
  wsplitT_k<64><<<64,  256, 0, stream>>>(dw1, whT1, wlT1, 256);
  wsplitT_k<256><<<128, 256, 0, stream>>>(dw2, whT2, wlT2, 128);

  for (int c0 = 0; c0 < 32; c0 += CB) {
    const float* xc = x + (size_t)c0 * 3 * 65536;
    float* outc = out + (size_t)c0 * 3 * 65536;
    // zero h1 + h2 plane borders (interiors fully overwritten each pass)
    {
      int nb1 = 2 * 130 + 2 * 128;
      int tot1 = CB * 16 * 2 * nb1;
      border_k<<<(tot1 + 255) / 256, 256, 0, stream>>>(
          (char*)A, 16, 130, 130, SAI, H1LOFF, CB);
      int nb2 = 2 * 66 + 2 * 64;
      int tot2 = CB * 32 * 2 * nb2;
      border_k<<<(tot2 + 255) / 256, 256, 0, stream>>>(
          (char*)Bp, 32, 66, 66, SBI, H2LOFF, CB);
    }
    // encoder (full split, bit-identical)
    conv_t<3, 16, 1, 2><<<dim3(64, CB * 8), 256, 0, stream>>>(
        xc, ew1, eb1, A, 128, 256, 256, SAI, H1LOFF);
    conv_mfma2<128, 256, 1, 2, 1, 2><<<dim3(128, CB), 256, 0, stream>>>(
        (const void*)A, wh2, wl2, eb2, Bp, 128, 128, SAI, H1LOFF, SBI, H2LOFF);
    conv_mfma2<256, 512, 2, 2, 1, 0><<<dim3(32, CB * 2), 256, 0, stream>>>(
        (const void*)Bp, wh3, wl3, eb3, A, 64, 64, SBI, H2LOFF, 0, 0);
    conv1x1_k<512, 4><<<dim3(4, CB * 16), 256, 0, stream>>>(A, pw, pb, ze, 64, 1024);
    vq_k<<<CB * 8, 128, 0, stream>>>(ze, emb, zq, part + (size_t)c0 * 8);
    // decoder: convT1/convT2 f16 h-only (SPLITX=0), R13 shapes
    convT_mfma<64, 256, 4, 1, 0, 1, 1, 0><<<dim3(32, CB * 4), 256, 0, stream>>>(
        zq, whT1, wlT1, db1, Bp, 32, 32);
    convT_mfma<256, 128, 2, 1, 1, 0, 1, 0><<<dim3(128, CB * 2), 256, 0, stream>>>(
        Bp, whT2, wlT2, db2, A, 64, 64);
    convT_t<128, 3, 2><<<dim3(64, CB * 1), 256, 0, stream>>>(A, dw3, db3, outc, 3, 128, 128);
  }
  loss_fin<<<1, 256, 0, stream>>>(part, out + (size_t)(out_size - 1));
}

// Round 16
// 2118.944 us; speedup vs baseline: 1.3672x; 1.0300x over previous
//
#include <hip/hip_runtime.h>
#include <cstddef>
#include <cstdint>

typedef __attribute__((ext_vector_type(8))) _Float16 half8;
typedef __attribute__((ext_vector_type(4))) _Float16 half4;
typedef __attribute__((ext_vector_type(4))) float f32x4;

static __device__ __forceinline__ unsigned packhl(float v) {
  _Float16 h = (_Float16)v;
  _Float16 l = (_Float16)((v - (float)h) * 2048.0f);
  return (unsigned)__builtin_bit_cast(unsigned short, h) |
         ((unsigned)__builtin_bit_cast(unsigned short, l) << 16);
}

// ---------------------------------------------------------------------------
// VQ-VAE forward. R16 = R15 (2183us) + convT3 (convT_t) IC-blocked staging
// (ICB=8: 16 rounds/32 barriers instead of 128/256). Math order identical.
// Encoder full 2-term split (argmin/loss bit-identical); decoder f16 h-only.
// ---------------------------------------------------------------------------

// Pre-split conv weights: W[Cout][CIN][4][4] -> [tap][cb][k8][cout][8] f16 h/l
template<int CIN>
__global__ __launch_bounds__(256) void wsplit_k(
    const float* __restrict__ W, _Float16* __restrict__ Wh,
    _Float16* __restrict__ Wl, int Cout) {
  constexpr int NCB = CIN / 32;
  int idx = blockIdx.x * 256 + threadIdx.x;
  if (idx >= Cout * CIN) return;
  int ci = idx % CIN, co = idx / CIN;
  int cb = ci >> 5, k8 = (ci >> 3) & 3, j = ci & 7;
  const float* wp = W + (size_t)idx * 16;
#pragma unroll
  for (int tap = 0; tap < 16; ++tap) {
    float w = wp[tap];
    _Float16 wh = (_Float16)w;
    _Float16 wl = (_Float16)((w - (float)wh) * 2048.0f);
    size_t o = (((size_t)(tap * NCB + cb) * 4 + k8) * Cout + co) * 8 + j;
    Wh[o] = wh; Wl[o] = wl;
  }
}

// Pre-split convT weights: W[CIN][Cout][4][4] -> [t][cb][k8][cout][8] f16 h/l
template<int CIN>
__global__ __launch_bounds__(256) void wsplitT_k(
    const float* __restrict__ W, _Float16* __restrict__ Wh,
    _Float16* __restrict__ Wl, int Cout) {
  constexpr int NCB = CIN / 32;
  int idx = blockIdx.x * 256 + threadIdx.x;
  if (idx >= CIN * Cout) return;
  int co = idx % Cout, ci = idx / Cout;
  int cb = ci >> 5, k8 = (ci >> 3) & 3, j = ci & 7;
  const float* wp = W + (size_t)idx * 16;
#pragma unroll
  for (int t = 0; t < 16; ++t) {
    int py = (t >> 3) & 1, px = (t >> 2) & 1, i0 = (t >> 1) & 1, i1 = t & 1;
    int kh = py ? (i0 ? 2 : 0) : (i0 ? 3 : 1);
    int kw = px ? (i1 ? 2 : 0) : (i1 ? 3 : 1);
    float w = wp[kh * 4 + kw];
    _Float16 wh = (_Float16)w;
    _Float16 wl = (_Float16)((w - (float)wh) * 2048.0f);
    size_t o = (((size_t)(t * NCB + cb) * 4 + k8) * Cout + co) * 8 + j;
    Wh[o] = wh; Wl[o] = wl;
  }
}

// Zero the 1-px border of split h/l planes. H2/W2 = padded dims.
__global__ __launch_bounds__(256) void border_k(
    char* base, int c8n, int H2, int W2, size_t SAI, size_t LOFF, int nimg) {
  int nb = 2 * W2 + 2 * (H2 - 2);
  int tot = nimg * c8n * 2 * nb;
  int idx = blockIdx.x * 256 + threadIdx.x;
  if (idx >= tot) return;
  int s = idx % nb; int r = idx / nb;
  int pl = r & 1; r >>= 1;
  int c8 = r % c8n; int b = r / c8n;
  int y, x;
  if (s < W2)            { y = 0;       x = s; }
  else if (s < 2 * W2)   { y = H2 - 1;  x = s - W2; }
  else { int t = s - 2 * W2; y = 1 + (t >> 1); x = (t & 1) ? W2 - 1 : 0; }
  size_t PLANE = (size_t)H2 * W2 * 16;
  char* p = base + (size_t)b * SAI + (size_t)pl * LOFF + (size_t)c8 * PLANE
            + ((size_t)y * W2 + x) * 16;
  *(uint4*)p = make_uint4(0, 0, 0, 0);
}

// MFMA conv k4 s2 p1 (+ReLU). Split-plane input staged via global_load_lds.
// PACKOUT: 0 = f32 NCHW, 2 = split h/l planes (+border).   (R13-verified)
template<int CIN, int COUT, int CGRP, int NF, int RELU, int PACKOUT>
__global__ __launch_bounds__(256) void conv_mfma2(
    const void* __restrict__ inP, const _Float16* __restrict__ Whg,
    const _Float16* __restrict__ Wlg, const float* __restrict__ bias,
    float* __restrict__ out, int Hin, int Win,
    size_t inSAI, size_t inLOFF, size_t outSAI, size_t outLOFF) {
  constexpr int NCB  = CIN / 32;
  constexpr int MT   = COUT / CGRP;
  constexpr int MF   = MT / 64;
  constexpr int ROWS = 2 * NF + 2;
  constexpr int NPOS = ROWS * 34;
  constexpr int K8S  = NPOS + 6;
  const int Hout = Hin >> 1, Wout = Win >> 1;
  const int TW = Wout >> 4;
  __shared__ half8 Bh[4 * K8S], Bl[4 * K8S];
  const int tid = threadIdx.x;
  const int lane = tid & 63, w = tid >> 6;
  const int l15 = lane & 15, k8 = lane >> 4;
  int tx, ty, cg, b;
  {
    unsigned nwg = gridDim.x * gridDim.y;
    unsigned id  = blockIdx.y * gridDim.x + blockIdx.x;
    unsigned sw  = (id & 7) * (nwg >> 3) + (id >> 3);
    const int bx = sw % gridDim.x, by = sw / gridDim.x;
    tx = bx % TW; ty = bx / TW;
    cg = by % CGRP;
    b  = by / CGRP;
  }
  const int oy0 = ty * NF, ox0 = tx << 4;
  const int iy_org = 2 * oy0 - 1, ix_org = 2 * ox0 - 1;
  const int cbase = cg * MT + w * (MT / 4);
  const size_t tapStride = (size_t)NCB * 4 * COUT * 8;

  unsigned goff[4];
  const char* baseh;
  size_t PLANE;
  {
    const int W2 = Win + 2;
    PLANE = (size_t)(Hin + 2) * W2 * 16;
    constexpr int S0[4] = {0, 64, 128, NPOS - 64};
#pragma unroll
    for (int t = 0; t < 4; ++t) {
      int s = S0[t] + lane;
      int r = s / 17, c = s - r * 17;
      int hy = r >> 1, p = r & 1;
      int hx = (c << 1) | p;
      int iy = iy_org + hy + 1, ix = ix_org + hx + 1;
      goff[t] = (unsigned)(((size_t)iy * W2 + ix) * 16);
    }
    baseh = (const char*)inP + ((size_t)b * inSAI) + (size_t)w * PLANE;
  }

  f32x4 accM[MF][NF], accX[MF][NF];
#pragma unroll
  for (int m = 0; m < MF; ++m)
#pragma unroll
    for (int nf = 0; nf < NF; ++nf) {
      accM[m][nf] = f32x4{0,0,0,0};
      accX[m][nf] = f32x4{0,0,0,0};
    }

  for (int cb = 0; cb < NCB; ++cb) {
    __syncthreads();
    {
      const char* pc = baseh + (size_t)cb * 4 * PLANE;
      char* lh = (char*)&Bh[w * K8S];
      char* ll = (char*)&Bl[w * K8S];
      constexpr int S0[4] = {0, 64, 128, NPOS - 64};
#pragma unroll
      for (int t = 0; t < 4; ++t) {
        __builtin_amdgcn_global_load_lds(
            (const __attribute__((address_space(1))) void*)(pc + goff[t]),
            (__attribute__((address_space(3))) void*)(lh + S0[t] * 16), 16, 0, 0);
        __builtin_amdgcn_global_load_lds(
            (const __attribute__((address_space(1))) void*)(pc + inLOFF + goff[t]),
            (__attribute__((address_space(3))) void*)(ll + S0[t] * 16), 16, 0, 0);
      }
    }
    __syncthreads();
    const _Float16* aph = Whg + (((size_t)cb * 4 + k8) * COUT + cbase + l15) * 8;
    const _Float16* apl = Wlg + (((size_t)cb * 4 + k8) * COUT + cbase + l15) * 8;
    half8 ah[2][MF], al[2][MF];
#pragma unroll
    for (int m = 0; m < MF; ++m) {
      ah[0][m] = *(const half8*)(aph + m * 128);
      al[0][m] = *(const half8*)(apl + m * 128);
    }
#pragma unroll
    for (int tp = 0; tp < 16; ++tp) {
      const int cur = tp & 1, nxt = cur ^ 1;
      if (tp < 15) {
#pragma unroll
        for (int m = 0; m < MF; ++m) {
          ah[nxt][m] = *(const half8*)(aph + (size_t)(tp + 1) * tapStride + m * 128);
          al[nxt][m] = *(const half8*)(apl + (size_t)(tp + 1) * tapStride + m * 128);
        }
      }
      const int kh = tp >> 2, kw = tp & 3;
      const int p = kw & 1, cidx = kw >> 1;
#pragma unroll
      for (int nf = 0; nf < NF; ++nf) {
        const int slot = k8 * K8S + ((2 * nf + kh) * 2 + p) * 17 + l15 + cidx;
        const half8 bh = Bh[slot], bl = Bl[slot];
#pragma unroll
        for (int m = 0; m < MF; ++m) {
          accM[m][nf] = __builtin_amdgcn_mfma_f32_16x16x32_f16(ah[cur][m], bh, accM[m][nf], 0, 0, 0);
          accX[m][nf] = __builtin_amdgcn_mfma_f32_16x16x32_f16(ah[cur][m], bl, accX[m][nf], 0, 0, 0);
          accX[m][nf] = __builtin_amdgcn_mfma_f32_16x16x32_f16(al[cur][m], bh, accX[m][nf], 0, 0, 0);
        }
      }
    }
  }
  // ---- epilogue ----
#pragma unroll
  for (int m = 0; m < MF; ++m)
#pragma unroll
    for (int nf = 0; nf < NF; ++nf) {
      int oy = oy0 + nf, ox = ox0 + l15;
      if (PACKOUT == 2) {
        const int W2o = Wout + 2;
        const size_t PLANEo = (size_t)(Hout + 2) * W2o * 16;
        half4 hv, lv;
#pragma unroll
        for (int i = 0; i < 4; ++i) {
          int co = cbase + m * 16 + k8 * 4 + i;
          float v = accM[m][nf][i] + accX[m][nf][i] * (1.0f / 2048.0f) + bias[co];
          if (RELU) v = fmaxf(v, 0.0f);
          _Float16 h = (_Float16)v;
          hv[i] = h; lv[i] = (_Float16)((v - (float)h) * 2048.0f);
        }
        int c8 = (cbase + m * 16 + k8 * 4) >> 3;
        int j0 = (k8 & 1) * 4;
        char* ob = (char*)out + (size_t)b * outSAI + (size_t)c8 * PLANEo
                   + (((size_t)(oy + 1) * W2o) + ox + 1) * 16 + j0 * 2;
        *(half4*)ob = hv;
        *(half4*)(ob + outLOFF) = lv;
      } else {
#pragma unroll
        for (int i = 0; i < 4; ++i) {
          int co = cbase + m * 16 + k8 * 4 + i;
          float v = accM[m][nf][i] + accX[m][nf][i] * (1.0f / 2048.0f) + bias[co];
          if (RELU) v = fmaxf(v, 0.0f);
          out[(((size_t)b * COUT + co) * Hout + oy) * Wout + ox] = v;
        }
      }
    }
}

// MFMA convT k4 s2 p1 (+ReLU). Parity decomposition (R13 shape).
// PACKIN: 0 = f32 NCHW, 1 = packed u32 interleave.
// PACKOUT: 0 = f32 NCHW, 1 = packed u32 interleave.
// SPLITX: 1 = full 2-term split (3 MFMA/tap); 0 = f16 h-only (1 MFMA/tap).
template<int CIN, int COUT, int CGRP, int RELU, int PACKIN, int PACKOUT,
         int SWZ, int SPLITX>
__global__ __launch_bounds__(256) void convT_mfma(
    const float* __restrict__ in, const _Float16* __restrict__ Whg,
    const _Float16* __restrict__ Wlg, const float* __restrict__ bias,
    float* __restrict__ out, int Hin, int Win) {
  constexpr int NCB = CIN / 32;
  constexpr int MT  = COUT / CGRP;
  constexpr int MF  = MT / 64;
  const int Hout = Hin * 2, Wout = Win * 2;
  const int TW = Win >> 4;
  __shared__ half8 Bh[4 * 72];
  __shared__ half8 Bl[SPLITX ? 4 * 72 : 1];
  const int tid = threadIdx.x;
  const int lane = tid & 63, w = tid >> 6;
  const int l15 = lane & 15, k8 = lane >> 4;
  int bx = blockIdx.x, by = blockIdx.y;
  if (SWZ) {
    unsigned nwg = gridDim.x * gridDim.y;
    unsigned id  = (unsigned)by * gridDim.x + bx;
    unsigned sw  = (id & 7) * (nwg >> 3) + (id >> 3);
    bx = (int)(sw % gridDim.x); by = (int)(sw / gridDim.x);
  }
  const int tx = bx % TW, ty = bx / TW;
  const int cg = by % CGRP;
  const int b  = by / CGRP;
  const int ty0 = ty << 1, tx0 = tx << 4;
  const int cbase = cg * MT + w * (MT / 4);
  const size_t HW = (size_t)Hin * Win;
  const size_t tapStride = (size_t)NCB * 4 * COUT * 8;

  f32x4 accM[MF][4][2], accX[SPLITX ? MF : 1][4][2];
#pragma unroll
  for (int m = 0; m < MF; ++m)
#pragma unroll
    for (int p = 0; p < 4; ++p)
#pragma unroll
      for (int nf = 0; nf < 2; ++nf) {
        accM[m][p][nf] = f32x4{0,0,0,0};
        if (SPLITX) accX[m][p][nf] = f32x4{0,0,0,0};
      }

  for (int cb = 0; cb < NCB; ++cb) {
    __syncthreads();
    for (int u = tid; u < 288; u += 256) {
      int pos = u % 72, kk = u / 72;
      int r = pos / 18, c = pos - r * 18;
      int iy = ty0 - 1 + r, ix = tx0 - 1 + c;
      bool ok = (unsigned)iy < (unsigned)Hin && (unsigned)ix < (unsigned)Win;
      half8 vh, vl;
      if (PACKIN) {
        uint4 qa = {0,0,0,0}, qb = {0,0,0,0};
        if (ok) {
          const uint4* gp = (const uint4*)((const unsigned*)in +
              (((size_t)b * (CIN / 8) + cb * 4 + kk) * HW + (size_t)iy * Win + ix) * 8);
          qa = gp[0]; qb = gp[1];
        }
        unsigned av[8] = {qa.x, qa.y, qa.z, qa.w, qb.x, qb.y, qb.z, qb.w};
#pragma unroll
        for (int j = 0; j < 8; ++j) {
          vh[j] = __builtin_bit_cast(_Float16, (unsigned short)(av[j] & 0xffffu));
          if (SPLITX)
            vl[j] = __builtin_bit_cast(_Float16, (unsigned short)(av[j] >> 16));
        }
      } else {
        const float* gp = in + ((size_t)b * CIN + cb * 32 + kk * 8) * HW
                          + (ptrdiff_t)iy * Win + ix;
#pragma unroll
        for (int j = 0; j < 8; ++j) {
          float x = ok ? gp[(size_t)j * HW] : 0.0f;
          _Float16 xh = (_Float16)x;
          vh[j] = xh;
          if (SPLITX) vl[j] = (_Float16)((x - (float)xh) * 2048.0f);
        }
      }
      Bh[kk * 72 + pos] = vh;
      if (SPLITX) Bl[kk * 72 + pos] = vl;
    }
    __syncthreads();
    const _Float16* aph = Whg + (((size_t)cb * 4 + k8) * COUT + cbase + l15) * 8;
    const _Float16* apl = Wlg + (((size_t)cb * 4 + k8) * COUT + cbase + l15) * 8;
    half8 ah[2][MF], al[2][MF];
#pragma unroll
    for (int m = 0; m < MF; ++m) {
      ah[0][m] = *(const half8*)(aph + m * 128);
      if (SPLITX) al[0][m] = *(const half8*)(apl + m * 128);
    }
#pragma unroll
    for (int t = 0; t < 16; ++t) {
      const int cur = t & 1, nxt = cur ^ 1;
      if (t < 15) {
#pragma unroll
        for (int m = 0; m < MF; ++m) {
          ah[nxt][m] = *(const half8*)(aph + (size_t)(t + 1) * tapStride + m * 128);
          if (SPLITX)
            al[nxt][m] = *(const half8*)(apl + (size_t)(t + 1) * tapStride + m * 128);
        }
      }
      const int py = (t >> 3) & 1, px = (t >> 2) & 1;
      const int i0 = (t >> 1) & 1, i1 = t & 1;
      const int dy = py ? (i0 ? 0 : 1) : (i0 ? -1 : 0);
      const int dx = px ? (i1 ? 0 : 1) : (i1 ? -1 : 0);
      const int p = py * 2 + px;
#pragma unroll
      for (int nf = 0; nf < 2; ++nf) {
        int slot = k8 * 72 + (nf + 1 + dy) * 18 + (l15 + 1 + dx);
        half8 bh = Bh[slot];
#pragma unroll
        for (int m = 0; m < MF; ++m) {
          accM[m][p][nf] = __builtin_amdgcn_mfma_f32_16x16x32_f16(ah[cur][m], bh, accM[m][p][nf], 0, 0, 0);
          if (SPLITX) {
            half8 bl = Bl[slot];
            accX[m][p][nf] = __builtin_amdgcn_mfma_f32_16x16x32_f16(ah[cur][m], bl, accX[m][p][nf], 0, 0, 0);
            accX[m][p][nf] = __builtin_amdgcn_mfma_f32_16x16x32_f16(al[cur][m], bh, accX[m][p][nf], 0, 0, 0);
          }
        }
      }
    }
  }
#pragma unroll
  for (int m = 0; m < MF; ++m) {
    const int co0m = cbase + m * 16;
#pragma unroll
    for (int nf = 0; nf < 2; ++nf) {
#pragma unroll
      for (int i = 0; i < 4; ++i) {
        int co = co0m + k8 * 4 + i;
        float bb = bias[co];
#pragma unroll
        for (int py = 0; py < 2; ++py) {
          float v0, v1;
          if (SPLITX) {
            v0 = accM[m][py * 2 + 0][nf][i] + accX[m][py * 2 + 0][nf][i] * (1.0f / 2048.0f) + bb;
            v1 = accM[m][py * 2 + 1][nf][i] + accX[m][py * 2 + 1][nf][i] * (1.0f / 2048.0f) + bb;
          } else {
            v0 = accM[m][py * 2 + 0][nf][i] + bb;
            v1 = accM[m][py * 2 + 1][nf][i] + bb;
          }
          if (RELU) { v0 = fmaxf(v0, 0.0f); v1 = fmaxf(v1, 0.0f); }
          int oy = 2 * (ty0 + nf) + py, ox = 2 * (tx0 + l15);
          if (PACKOUT) {
            unsigned* outU = (unsigned*)out;
            int co8 = (co0m >> 3) + (k8 >> 1);
            int j = (k8 * 4 + i) & 7;
            size_t base = ((size_t)b * (COUT / 8) + co8) * ((size_t)Hout * Wout);
            outU[(base + (size_t)oy * Wout + ox) * 8 + j]     = packhl(v0);
            outU[(base + (size_t)oy * Wout + ox + 1) * 8 + j] = packhl(v1);
          } else {
            *(float2*)(out + (((size_t)b * COUT + co) * Hout + oy) * Wout + ox) =
                make_float2(v0, v1);
          }
        }
      }
    }
  }
}

// ---------------- f32 kernels ----------------------------------------------

template<int CIN, int G, int RELU, int PACKOUT>
__global__ __launch_bounds__(256) void conv_t(
    const float* __restrict__ in, const float* __restrict__ wt,
    const float* __restrict__ bias, float* __restrict__ out,
    int Cout, int Hin, int Win, size_t oSAI, size_t oLOFF) {
  const int Hout = Hin >> 1, Wout = Win >> 1;
  const int TW = Wout >> 4;
  __shared__ float tile[34 * 35];
  int tid = threadIdx.x;
  int oxl = tid & 15, oyl = tid >> 4;
  int tyt = blockIdx.x / TW, txt = blockIdx.x - tyt * TW;
  int oy0 = tyt << 4, ox0 = txt << 4;
  int cg = blockIdx.y % (Cout / G);
  int b  = blockIdx.y / (Cout / G);
  int co0 = cg * G;
  const int iy_org = 2 * oy0 - 1, ix_org = 2 * ox0 - 1;
  const float* ip = in + (size_t)b * CIN * Hin * Win;
  float acc[G];
#pragma unroll
  for (int j = 0; j < G; ++j) acc[j] = bias[co0 + j];
  const int lbase = (2 * oyl) * 35 + 2 * oxl;
  for (int ci = 0; ci < CIN; ++ci) {
    const float* ic = ip + (size_t)ci * Hin * Win;
    __syncthreads();
#pragma unroll
    for (int k = 0; k < 5; ++k) {
      int idx = tid + k * 256;
      if (idx < 34 * 34) {
        int r = idx / 34, c = idx - r * 34;
        int iy = iy_org + r, ix = ix_org + c;
        float v = ((unsigned)iy < (unsigned)Hin && (unsigned)ix < (unsigned)Win)
                      ? ic[(size_t)iy * Win + ix] : 0.0f;
        tile[r * 35 + c] = v;
      }
    }
    __syncthreads();
    float xv[16];
#pragma unroll
    for (int kh = 0; kh < 4; ++kh)
#pragma unroll
      for (int kw = 0; kw < 4; ++kw)
        xv[kh * 4 + kw] = tile[lbase + kh * 35 + kw];
    const float* wc = wt + ((size_t)co0 * CIN + ci) * 16;
#pragma unroll
    for (int j = 0; j < G; ++j) {
      const float* wj = wc + (size_t)j * CIN * 16;
#pragma unroll
      for (int t2 = 0; t2 < 16; ++t2) acc[j] = fmaf(xv[t2], wj[t2], acc[j]);
    }
  }
  int oy = oy0 + oyl, ox = ox0 + oxl;
  if (RELU) {
#pragma unroll
    for (int j = 0; j < G; ++j) acc[j] = fmaxf(acc[j], 0.0f);
  }
  if (PACKOUT == 2) {
    const int W2 = Wout + 2;
    const size_t PLANE = (size_t)(Hout + 2) * W2 * 16;
    char* ob0 = (char*)out + (size_t)b * oSAI
                + ((size_t)(oy + 1) * W2 + ox + 1) * 16;
#pragma unroll
    for (int mb = 0; mb < G / 8; ++mb) {
      half8 hv, lv;
#pragma unroll
      for (int j = 0; j < 8; ++j) {
        float v = acc[mb * 8 + j];
        _Float16 h = (_Float16)v;
        hv[j] = h; lv[j] = (_Float16)((v - (float)h) * 2048.0f);
      }
      char* ob = ob0 + (size_t)((co0 >> 3) + mb) * PLANE;
      *(half8*)ob = hv;
      *(half8*)(ob + oLOFF) = lv;
    }
  } else {
    size_t cs = (size_t)Hout * Wout;
    float* op = out + ((size_t)(b * Cout + co0) * Hout + oy) * Wout + ox;
#pragma unroll
    for (int j = 0; j < G; ++j) op[(size_t)j * cs] = acc[j];
  }
}

template<int CIN, int G>
__global__ __launch_bounds__(256) void conv1x1_k(
    const float* __restrict__ in, const float* __restrict__ wt,
    const float* __restrict__ bias, float* __restrict__ out,
    int Cout, int HW) {
  int hw = blockIdx.x * 256 + threadIdx.x;
  int cg = blockIdx.y % (Cout / G);
  int b  = blockIdx.y / (Cout / G);
  int co0 = cg * G;
  const float* ip = in + (size_t)b * CIN * HW + hw;
  float acc[G];
#pragma unroll
  for (int j = 0; j < G; ++j) acc[j] = bias[co0 + j];
#pragma unroll 4
  for (int ci = 0; ci < CIN; ++ci) {
    float xv = ip[(size_t)ci * HW];
#pragma unroll
    for (int j = 0; j < G; ++j)
      acc[j] = fmaf(xv, wt[(size_t)(co0 + j) * CIN + ci], acc[j]);
  }
  float* op = out + ((size_t)(b * Cout + co0)) * HW + hw;
#pragma unroll
  for (int j = 0; j < G; ++j) op[(size_t)j * HW] = acc[j];
}

__global__ __launch_bounds__(128) void vq_k(
    const float* __restrict__ ze, const float* __restrict__ emb,
    float* __restrict__ zq, float* __restrict__ partial) {
  __shared__ float4 se4[128 * 16];
  __shared__ float red[128];
  int tid = threadIdx.x;
  int gid = blockIdx.x * 128 + tid;
  int b = gid >> 10, n = gid & 1023;
  const float* zp = ze + ((size_t)b << 16) + n;
  float4 v4[16];
#pragma unroll
  for (int d = 0; d < 16; ++d) {
    v4[d].x = zp[(size_t)(4 * d + 0) << 10];
    v4[d].y = zp[(size_t)(4 * d + 1) << 10];
    v4[d].z = zp[(size_t)(4 * d + 2) << 10];
    v4[d].w = zp[(size_t)(4 * d + 3) << 10];
  }
  float best = 1e30f; int bi = 0;
  for (int c = 0; c < 4; ++c) {
    __syncthreads();
    for (int i = tid; i < 2048; i += 128)
      se4[i] = ((const float4*)emb)[(c << 11) + i];
    __syncthreads();
    for (int k = 0; k < 128; ++k) {
      const float4* e = se4 + (k << 4);
      float s = 0.0f;
#pragma unroll
      for (int d = 0; d < 16; ++d) {
        float4 ev = e[d];
        float t0 = v4[d].x - ev.x; s = fmaf(t0, t0, s);
        float t1 = v4[d].y - ev.y; s = fmaf(t1, t1, s);
        float t2 = v4[d].z - ev.z; s = fmaf(t2, t2, s);
        float t3 = v4[d].w - ev.w; s = fmaf(t3, t3, s);
      }
      if (s < best) { best = s; bi = (c << 7) + k; }
    }
  }
  const float4* eb4 = (const float4*)emb + ((size_t)bi << 4);
  float* qp = zq + ((size_t)b << 16) + n;
  float ls = 0.0f;
#pragma unroll
  for (int d = 0; d < 16; ++d) {
    float4 q = eb4[d];
    qp[(size_t)(4 * d + 0) << 10] = q.x;
    qp[(size_t)(4 * d + 1) << 10] = q.y;
    qp[(size_t)(4 * d + 2) << 10] = q.z;
    qp[(size_t)(4 * d + 3) << 10] = q.w;
    float t0 = q.x - v4[d].x; ls = fmaf(t0, t0, ls);
    float t1 = q.y - v4[d].y; ls = fmaf(t1, t1, ls);
    float t2 = q.z - v4[d].z; ls = fmaf(t2, t2, ls);
    float t3 = q.w - v4[d].w; ls = fmaf(t3, t3, ls);
  }
  red[tid] = ls;
  __syncthreads();
  for (int s = 64; s > 0; s >>= 1) {
    if (tid < s) red[tid] += red[tid + s];
    __syncthreads();
  }
  if (tid == 0) partial[blockIdx.x] = red[0];
}

__global__ __launch_bounds__(256) void loss_fin(
    const float* __restrict__ partial, float* __restrict__ out) {
  __shared__ float red[256];
  int t = threadIdx.x;
  red[t] = partial[t];
  __syncthreads();
  for (int s = 128; s > 0; s >>= 1) {
    if (t < s) red[t] += red[t + s];
    __syncthreads();
  }
  if (t == 0) out[0] = red[0] * (2.0f / 2097152.0f);
}

// ConvTranspose2d k4 s2 p1 (+ReLU/sigmoid), f32, IC-blocked staging (R16).
// Per round: stage ICB channels' 18x18 halo (pitch 19), then accumulate.
// Accumulation order per output = ci ascending (bit-identical to R15).
template<int CIN, int ICB, int G, int ACT>
__global__ __launch_bounds__(256) void convT_t(
    const float* __restrict__ in, const float* __restrict__ wt,
    const float* __restrict__ bias, float* __restrict__ out,
    int Cout, int Hin, int Win) {
  constexpr int NR = CIN / ICB;
  const int Hout = Hin * 2, Wout = Win * 2;
  const int TW = Win >> 4;
  __shared__ float tile[ICB][18 * 19];
  int tid = threadIdx.x;
  int txl = tid & 15, tyl = tid >> 4;
  int tyt = blockIdx.x / TW, txt = blockIdx.x - tyt * TW;
  int ty0 = tyt << 4, tx0 = txt << 4;
  int og = blockIdx.y % (Cout / G);
  int b  = blockIdx.y / (Cout / G);
  int o0 = og * G;
  const int iy_org = ty0 - 1, ix_org = tx0 - 1;
  const float* ip = in + (size_t)b * CIN * Hin * Win;
  float a00[G], a01[G], a10[G], a11[G];
#pragma unroll
  for (int j = 0; j < G; ++j) {
    float bb = bias[o0 + j];
    a00[j] = bb; a01[j] = bb; a10[j] = bb; a11[j] = bb;
  }
  const int lb = tyl * 19 + txl;
  for (int r0 = 0; r0 < NR; ++r0) {
    __syncthreads();
    for (int u = tid; u < ICB * 324; u += 256) {
      int kk = u / 324, pos = u - kk * 324;
      int r = pos / 18, c = pos - r * 18;
      int iy = iy_org + r, ix = ix_org + c;
      float v = ((unsigned)iy < (unsigned)Hin && (unsigned)ix < (unsigned)Win)
                    ? ip[(size_t)(r0 * ICB + kk) * Hin * Win + (size_t)iy * Win + ix]
                    : 0.0f;
      tile[kk][r * 19 + c] = v;
    }
    __syncthreads();
#pragma unroll
    for (int kk = 0; kk < ICB; ++kk) {
      const float* tl = &tile[kk][0];
      float x00 = tl[lb],      x01 = tl[lb + 1],  x02 = tl[lb + 2];
      float x10 = tl[lb + 19], x11 = tl[lb + 20], x12 = tl[lb + 21];
      float x20 = tl[lb + 38], x21 = tl[lb + 39], x22 = tl[lb + 40];
      const float* wv = wt + ((size_t)(r0 * ICB + kk) * Cout + o0) * 16;
#pragma unroll
      for (int j = 0; j < G; ++j) {
        const float* w4 = wv + j * 16;
        a00[j] = fmaf(x11, w4[5],  fmaf(x10, w4[7],  fmaf(x01, w4[13], fmaf(x00, w4[15], a00[j]))));
        a01[j] = fmaf(x12, w4[4],  fmaf(x11, w4[6],  fmaf(x02, w4[12], fmaf(x01, w4[14], a01[j]))));
        a10[j] = fmaf(x21, w4[1],  fmaf(x20, w4[3],  fmaf(x11, w4[9],  fmaf(x10, w4[11], a10[j]))));
        a11[j] = fmaf(x22, w4[0],  fmaf(x21, w4[2],  fmaf(x12, w4[8],  fmaf(x11, w4[10], a11[j]))));
      }
    }
  }
  size_t cs = (size_t)Hout * Wout;
  int ty = ty0 + tyl, tx = tx0 + txl;
  size_t base = ((size_t)(b * Cout + o0) * Hout + 2 * (size_t)ty) * Wout + 2 * tx;
#pragma unroll
  for (int j = 0; j < G; ++j) {
    float v00 = a00[j], v01 = a01[j], v10 = a10[j], v11 = a11[j];
    if (ACT == 1) {
      v00 = fmaxf(v00, 0.0f); v01 = fmaxf(v01, 0.0f);
      v10 = fmaxf(v10, 0.0f); v11 = fmaxf(v11, 0.0f);
    } else if (ACT == 2) {
      v00 = 1.0f / (1.0f + expf(-v00)); v01 = 1.0f / (1.0f + expf(-v01));
      v10 = 1.0f / (1.0f + expf(-v10)); v11 = 1.0f / (1.0f + expf(-v11));
    }
    *(float2*)(out + base + (size_t)j * cs)        = make_float2(v00, v01);
    *(float2*)(out + base + (size_t)j * cs + Wout) = make_float2(v10, v11);
  }
}

extern "C" void kernel_launch(void* const* d_in, const int* in_sizes, int n_in,
                              void* d_out, int out_size, void* d_ws, size_t ws_size,
                              hipStream_t stream) {
  const float* x   = (const float*)d_in[0];
  const float* ew1 = (const float*)d_in[1];
  const float* eb1 = (const float*)d_in[2];
  const float* ew2 = (const float*)d_in[3];
  const float* eb2 = (const float*)d_in[4];
  const float* ew3 = (const float*)d_in[5];
  const float* eb3 = (const float*)d_in[6];
  const float* pw  = (const float*)d_in[7];
  const float* pb  = (const float*)d_in[8];
  const float* emb = (const float*)d_in[9];
  const float* dw1 = (const float*)d_in[10];
  const float* db1 = (const float*)d_in[11];
  const float* dw2 = (const float*)d_in[12];
  const float* db2 = (const float*)d_in[13];
  const float* dw3 = (const float*)d_in[14];
  const float* db3 = (const float*)d_in[15];
  float* out = (float*)d_out;
  char* ws = (char*)d_ws;

  // h1 split planes: 16 c8 x 130x130x16B, h + l.
  const size_t H1PLANE = 130ull * 130ull * 16ull;        // 270400
  const size_t H1LOFF  = 16ull * H1PLANE;                // 4326400
  const size_t SAI     = 2ull * H1LOFF;                  // 8652800
  // h2 split planes: 32 c8 x 66x66x16B, h + l (d1 packed u32 aliases region).
  const size_t H2PLANE = 66ull * 66ull * 16ull;          // 69696
  const size_t H2LOFF  = 32ull * H2PLANE;                // 2230272
  const size_t SBI     = 2ull * H2LOFF;                  // 4460544
  const size_t PER  = SAI + SBI + 2ull * 262144ull;      // 13637632
  const size_t WEXT = 4096ull + 13631488ull;
  int CB = 32;
  while (CB > 1 && (size_t)CB * PER + WEXT > ws_size) CB >>= 1;
  const size_t SA = (size_t)CB * SAI;
  const size_t SB = (size_t)CB * SBI;
  const size_t SC = (size_t)CB * 262144ull;
  float* A    = (float*)(ws);              // h1(split) -> h3(f32) -> d2(f32)
  float* Bp   = (float*)(ws + SA);         // h2(split) -> d1(packed)
  float* ze   = (float*)(ws + SA + SB);
  float* zq   = (float*)(ws + SA + SB + SC);
  float* part = (float*)(ws + SA + SB + 2 * SC);
  _Float16* wh2  = (_Float16*)(ws + SA + SB + 2 * SC + 4096);
  _Float16* wl2  = wh2 + 524288;
  _Float16* wh3  = wl2 + 524288;
  _Float16* wl3  = wh3 + 2097152;
  _Float16* whT1 = wl3 + 2097152;
  _Float16* wlT1 = whT1 + 262144;
  _Float16* whT2 = wlT1 + 262144;
  _Float16* wlT2 = whT2 + 524288;

  wsplit_k<128><<<128, 256, 0, stream>>>(ew2, wh2, wl2, 256);
  wsplit_k<256><<<512, 256, 0, stream>>>(ew3, wh3, wl3, 512);
  wsplitT_k<64><<<64,  256, 0, stream>>>(dw1, whT1, wlT1, 256);
  wsplitT_k<256><<<128, 256, 0, stream>>>(dw2, whT2, wlT2, 128);

  for (int c0 = 0; c0 < 32; c0 += CB) {
    const float* xc = x + (size_t)c0 * 3 * 65536;
    float* outc = out + (size_t)c0 * 3 * 65536;
    // zero h1 + h2 plane borders (interiors fully overwritten each pass)
    {
      int nb1 = 2 * 130 + 2 * 128;
      int tot1 = CB * 16 * 2 * nb1;
      border_k<<<(tot1 + 255) / 256, 256, 0, stream>>>(
          (char*)A, 16, 130, 130, SAI, H1LOFF, CB);
      int nb2 = 2 * 66 + 2 * 64;
      int tot2 = CB * 32 * 2 * nb2;
      border_k<<<(tot2 + 255) / 256, 256, 0, stream>>>(
          (char*)Bp, 32, 66, 66, SBI, H2LOFF, CB);
    }
    // encoder (full split, bit-identical)
    conv_t<3, 16, 1, 2><<<dim3(64, CB * 8), 256, 0, stream>>>(
        xc, ew1, eb1, A, 128, 256, 256, SAI, H1LOFF);
    conv_mfma2<128, 256, 1, 2, 1, 2><<<dim3(128, CB), 256, 0, stream>>>(
        (const void*)A, wh2, wl2, eb2, Bp, 128, 128, SAI, H1LOFF, SBI, H2LOFF);
    conv_mfma2<256, 512, 2, 2, 1, 0><<<dim3(32, CB * 2), 256, 0, stream>>>(
        (const void*)Bp, wh3, wl3, eb3, A, 64, 64, SBI, H2LOFF, 0, 0);
    conv1x1_k<512, 4><<<dim3(4, CB * 16), 256, 0, stream>>>(A, pw, pb, ze, 64, 1024);
    vq_k<<<CB * 8, 128, 0, stream>>>(ze, emb, zq, part + (size_t)c0 * 8);
    // decoder: convT1/convT2 f16 h-only (SPLITX=0); convT3 f32 IC-blocked
    convT_mfma<64, 256, 4, 1, 0, 1, 1, 0><<<dim3(32, CB * 4), 256, 0, stream>>>(
        zq, whT1, wlT1, db1, Bp, 32, 32);
    convT_mfma<256, 128, 2, 1, 1, 0, 1, 0><<<dim3(128, CB * 2), 256, 0, stream>>>(
        Bp, whT2, wlT2, db2, A, 64, 64);
    convT_t<128, 8, 3, 2><<<dim3(64, CB * 1), 256, 0, stream>>>(
        A, dw3, db3, outc, 3, 128, 128);
  }
  loss_fin<<<1, 256, 0, stream>>>(part, out + (size_t)(out_size - 1));
}